// Round 1
// baseline (960.443 us; speedup 1.0000x reference)
//
#include <hip/hip_runtime.h>
#include <hip/hip_bf16.h>
#include <math.h>

#define NN 100000   // nodes
#define NE 300000   // edges per snapshot
#define NS 5        // snapshots
#define DIN 128
#define HID 256
#define NP 10000    // post nodes

// ---------------- CSR build ----------------

__global__ void count_kernel(const int* __restrict__ dst, int* __restrict__ cnt) {
    int i = blockIdx.x * blockDim.x + threadIdx.x;
    if (i < NE) atomicAdd(&cnt[dst[i]], 1);
}

__global__ void scan1_kernel(const int* __restrict__ cnt, int* __restrict__ offs,
                             int* __restrict__ bsum, int n) {
    __shared__ int s[256];
    int i = blockIdx.x * 256 + threadIdx.x;
    int v = (i < n) ? cnt[i] : 0;
    s[threadIdx.x] = v;
    __syncthreads();
    for (int d = 1; d < 256; d <<= 1) {
        int t = (threadIdx.x >= d) ? s[threadIdx.x - d] : 0;
        __syncthreads();
        s[threadIdx.x] += t;
        __syncthreads();
    }
    if (i < n) offs[i] = s[threadIdx.x] - v;      // exclusive within block
    if (threadIdx.x == 255) bsum[blockIdx.x] = s[255];
}

__global__ void scan2_kernel(int* __restrict__ bsum, int nb) {
    __shared__ int s[512];
    int i = threadIdx.x;
    int v = (i < nb) ? bsum[i] : 0;
    s[i] = v;
    __syncthreads();
    for (int d = 1; d < 512; d <<= 1) {
        int t = (i >= d) ? s[i - d] : 0;
        __syncthreads();
        s[i] += t;
        __syncthreads();
    }
    if (i < nb) bsum[i] = s[i] - v;               // exclusive
}

__global__ void scan3_kernel(int* __restrict__ offs, const int* __restrict__ bsum,
                             int* __restrict__ cursor, int n) {
    int i = blockIdx.x * 256 + threadIdx.x;
    if (i < n) {
        int o = offs[i] + bsum[blockIdx.x];
        offs[i] = o;
        cursor[i] = o;
    }
}

__global__ void dinv_kernel(const int* __restrict__ cnt, float* __restrict__ dinv, int n) {
    int i = blockIdx.x * blockDim.x + threadIdx.x;
    if (i < n) dinv[i] = rsqrtf((float)(cnt[i] + 1));   // +1 self loop, deg>=1 always
}

__global__ void fill_kernel(const int* __restrict__ src, const int* __restrict__ dst,
                            int* __restrict__ cursor, int* __restrict__ csr) {
    int i = blockIdx.x * blockDim.x + threadIdx.x;
    if (i < NE) {
        int d = dst[i];
        int pos = atomicAdd(&cursor[d], 1);
        csr[pos] = src[i];
    }
}

// ---------------- generic tiled f32 GEMM: C = alpha * A[M,K] @ B[K,Nc] ----------------
// Nc % 64 == 0, K % 16 == 0. Grid: (ceil(M/64), Nc/64), block 256.

__global__ void sgemm64_kernel(const float* __restrict__ A, const float* __restrict__ B,
                               float* __restrict__ C, int M, int Nc, int K, float alpha) {
    __shared__ float As[16][64];
    __shared__ float Bs[16][64];
    int tid = threadIdx.x;
    int tx = tid & 15;            // 0..15 -> col group
    int ty = tid >> 4;            // 0..15 -> row group
    int rowBase = blockIdx.x * 64;
    int colBase = blockIdx.y * 64;

    float acc[4][4];
    #pragma unroll
    for (int i = 0; i < 4; i++)
        #pragma unroll
        for (int j = 0; j < 4; j++) acc[i][j] = 0.f;

    int aRow = tid >> 2;              // 0..63
    int aCol = (tid & 3) * 4;         // 0,4,8,12
    int bRow = tid >> 4;              // 0..15
    int bCol = (tid & 15) * 4;        // 0..60

    for (int k0 = 0; k0 < K; k0 += 16) {
        // load A tile 64x16 (transposed into As[k][row])
        int gr = rowBase + aRow;
        float4 av = make_float4(0.f, 0.f, 0.f, 0.f);
        if (gr < M) av = *(const float4*)&A[(size_t)gr * K + k0 + aCol];
        As[aCol + 0][aRow] = av.x;
        As[aCol + 1][aRow] = av.y;
        As[aCol + 2][aRow] = av.z;
        As[aCol + 3][aRow] = av.w;
        // load B tile 16x64
        float4 bv = *(const float4*)&B[(size_t)(k0 + bRow) * Nc + colBase + bCol];
        *(float4*)&Bs[bRow][bCol] = bv;
        __syncthreads();

        #pragma unroll
        for (int kk = 0; kk < 16; kk++) {
            float4 a = *(const float4*)&As[kk][ty * 4];
            float4 b = *(const float4*)&Bs[kk][tx * 4];
            float aa[4] = {a.x, a.y, a.z, a.w};
            float bb[4] = {b.x, b.y, b.z, b.w};
            #pragma unroll
            for (int i = 0; i < 4; i++)
                #pragma unroll
                for (int j = 0; j < 4; j++) acc[i][j] += aa[i] * bb[j];
        }
        __syncthreads();
    }

    #pragma unroll
    for (int i = 0; i < 4; i++) {
        int r = rowBase + ty * 4 + i;
        if (r < M) {
            float4 o = make_float4(alpha * acc[i][0], alpha * acc[i][1],
                                   alpha * acc[i][2], alpha * acc[i][3]);
            *(float4*)&C[(size_t)r * Nc + colBase + tx * 4] = o;
        }
    }
}

// ---------------- layer-1 aggregation: x1 = relu(dinv*(sum dinv[s]*h1[s] + dinv*h1[i]) + b1)
// one wave per node, lane handles 4 of 256 cols

__global__ void agg1_kernel(const float* __restrict__ h1, const float* __restrict__ dinv,
                            const int* __restrict__ offs, const int* __restrict__ cnt,
                            const int* __restrict__ csr, const float* __restrict__ b1,
                            float* __restrict__ x1) {
    int wave = threadIdx.x >> 6;
    int lane = threadIdx.x & 63;
    int node = blockIdx.x * 4 + wave;
    if (node >= NN) return;
    int o = offs[node];
    int c = cnt[node];
    float di = dinv[node];
    float4 acc = make_float4(0.f, 0.f, 0.f, 0.f);
    for (int k = 0; k < c; k++) {
        int s = csr[o + k];
        float w = dinv[s];
        float4 h = *(const float4*)&h1[(size_t)s * HID + lane * 4];
        acc.x += w * h.x; acc.y += w * h.y; acc.z += w * h.z; acc.w += w * h.w;
    }
    float4 hs = *(const float4*)&h1[(size_t)node * HID + lane * 4];
    acc.x += di * hs.x; acc.y += di * hs.y; acc.z += di * hs.z; acc.w += di * hs.w;
    float4 bb = *(const float4*)&b1[lane * 4];
    float4 r;
    r.x = fmaxf(di * acc.x + bb.x, 0.f);
    r.y = fmaxf(di * acc.y + bb.y, 0.f);
    r.z = fmaxf(di * acc.z + bb.z, 0.f);
    r.w = fmaxf(di * acc.w + bb.w, 0.f);
    *(float4*)&x1[(size_t)node * HID + lane * 4] = r;
}

// ---------------- layer-2 pre-aggregation at post slots only (linearity of GCN conv)
// z2[p] = sum_{e into node} dinv[src]*x1[src] + dinv[node]*x1[node]

__global__ void z2_kernel(const float* __restrict__ x1, const float* __restrict__ dinv,
                          const int* __restrict__ offs, const int* __restrict__ cnt,
                          const int* __restrict__ csr, const int* __restrict__ post,
                          float* __restrict__ z2) {
    int wave = threadIdx.x >> 6;
    int lane = threadIdx.x & 63;
    int p = blockIdx.x * 4 + wave;
    if (p >= NP) return;
    int node = post[p];
    int o = offs[node];
    int c = cnt[node];
    float di = dinv[node];
    float4 acc = make_float4(0.f, 0.f, 0.f, 0.f);
    for (int k = 0; k < c; k++) {
        int s = csr[o + k];
        float w = dinv[s];
        float4 h = *(const float4*)&x1[(size_t)s * HID + lane * 4];
        acc.x += w * h.x; acc.y += w * h.y; acc.z += w * h.z; acc.w += w * h.w;
    }
    float4 hs = *(const float4*)&x1[(size_t)node * HID + lane * 4];
    acc.x += di * hs.x; acc.y += di * hs.y; acc.z += di * hs.z; acc.w += di * hs.w;
    *(float4*)&z2[(size_t)p * HID + lane * 4] = acc;
}

// aggP[p,:] += dinv[node]*tmp2[p,:] + b2[:] + x1[node,:]   (residual + bias + dst norm)
__global__ void epi2_kernel(const float* __restrict__ tmp2, const float* __restrict__ dinv,
                            const int* __restrict__ post, const float* __restrict__ b2,
                            const float* __restrict__ x1, float* __restrict__ aggP) {
    int i = blockIdx.x * blockDim.x + threadIdx.x;
    if (i < NP * HID) {
        int p = i >> 8;
        int j = i & 255;
        int nd = post[p];
        aggP[i] += dinv[nd] * tmp2[i] + b2[j] + x1[(size_t)nd * HID + j];
    }
}

// hid = relu(hid + bc1)
__global__ void epihid_kernel(float* __restrict__ hid, const float* __restrict__ bc1) {
    int i = blockIdx.x * blockDim.x + threadIdx.x;
    if (i < NP * 128) {
        float v = hid[i] + bc1[i & 127];
        hid[i] = v > 0.f ? v : 0.f;
    }
}

// out[p] = sigmoid(hid[p,:] . Wc2 + bc2) ; wave per p
__global__ void final_kernel(const float* __restrict__ hid, const float* __restrict__ Wc2,
                             const float* __restrict__ bc2, float* __restrict__ out) {
    int wave = threadIdx.x >> 6;
    int lane = threadIdx.x & 63;
    int p = blockIdx.x * 4 + wave;
    if (p >= NP) return;
    float part = hid[(size_t)p * 128 + lane] * Wc2[lane]
               + hid[(size_t)p * 128 + 64 + lane] * Wc2[64 + lane];
    for (int off = 32; off; off >>= 1) part += __shfl_down(part, off, 64);
    if (lane == 0) out[p] = 1.f / (1.f + expf(-(part + bc2[0])));
}

// ---------------- host ----------------

extern "C" void kernel_launch(void* const* d_in, const int* in_sizes, int n_in,
                              void* d_out, int out_size, void* d_ws, size_t ws_size,
                              hipStream_t stream) {
    const float* X    = (const float*)d_in[0];
    const int*   EI   = (const int*)d_in[1];   // [S,2,E] int32
    const int*   post = (const int*)d_in[2];
    const float* W1   = (const float*)d_in[3];
    const float* b1   = (const float*)d_in[4];
    const float* W2   = (const float*)d_in[5];
    const float* b2   = (const float*)d_in[6];
    const float* Wc1  = (const float*)d_in[7];
    const float* bc1  = (const float*)d_in[8];
    const float* Wc2  = (const float*)d_in[9];
    const float* bc2  = (const float*)d_in[10];
    float* out = (float*)d_out;

    // workspace carve
    char* w = (char*)d_ws;
    auto carve = [&](size_t bytes) {
        void* p = (void*)w;
        w += (bytes + 255) & ~(size_t)255;
        return p;
    };
    float* h1     = (float*)carve((size_t)NN * HID * 4);   // 102.4 MB
    float* x1     = (float*)carve((size_t)NN * HID * 4);   // 102.4 MB
    float* z2     = (float*)carve((size_t)NP * HID * 4);   // 10.2 MB
    float* tmp2   = (float*)carve((size_t)NP * HID * 4);   // 10.2 MB
    float* aggP   = (float*)carve((size_t)NP * HID * 4);   // 10.2 MB
    float* hid    = (float*)carve((size_t)NP * 128 * 4);   // 5.1 MB
    float* dinv   = (float*)carve((size_t)NN * 4);
    int*   cnt    = (int*)carve((size_t)NN * 4);
    int*   offs   = (int*)carve((size_t)NN * 4);
    int*   cursor = (int*)carve((size_t)NN * 4);
    int*   bsum   = (int*)carve(1024 * 4);
    int*   csr    = (int*)carve((size_t)NE * 4);

    const int NB_N = (NN + 255) / 256;   // 391

    hipMemsetAsync(aggP, 0, (size_t)NP * HID * 4, stream);

    // h1 = X @ W1 (snapshot invariant)
    {
        dim3 g((NN + 63) / 64, HID / 64);
        sgemm64_kernel<<<g, 256, 0, stream>>>(X, W1, h1, NN, HID, DIN, 1.0f);
    }

    for (int s = 0; s < NS; s++) {
        const int* src = EI + (size_t)s * 2 * NE;
        const int* dst = src + NE;

        hipMemsetAsync(cnt, 0, (size_t)NN * 4, stream);
        count_kernel<<<(NE + 255) / 256, 256, 0, stream>>>(dst, cnt);
        scan1_kernel<<<NB_N, 256, 0, stream>>>(cnt, offs, bsum, NN);
        scan2_kernel<<<1, 512, 0, stream>>>(bsum, NB_N);
        scan3_kernel<<<NB_N, 256, 0, stream>>>(offs, bsum, cursor, NN);
        dinv_kernel<<<NB_N, 256, 0, stream>>>(cnt, dinv, NN);
        fill_kernel<<<(NE + 255) / 256, 256, 0, stream>>>(src, dst, cursor, csr);

        agg1_kernel<<<(NN + 3) / 4, 256, 0, stream>>>(h1, dinv, offs, cnt, csr, b1, x1);
        z2_kernel<<<(NP + 3) / 4, 256, 0, stream>>>(x1, dinv, offs, cnt, csr, post, z2);
        {
            dim3 g((NP + 63) / 64, HID / 64);
            sgemm64_kernel<<<g, 256, 0, stream>>>(z2, W2, tmp2, NP, HID, HID, 1.0f);
        }
        epi2_kernel<<<(NP * HID + 255) / 256, 256, 0, stream>>>(tmp2, dinv, post, b2, x1, aggP);
    }

    // classifier: hid = relu((aggP/5) @ Wc1 + bc1); out = sigmoid(hid @ Wc2 + bc2)
    {
        dim3 g((NP + 63) / 64, 128 / 64);
        sgemm64_kernel<<<g, 256, 0, stream>>>(aggP, Wc1, hid, NP, 128, HID, 0.2f);
    }
    epihid_kernel<<<(NP * 128 + 255) / 256, 256, 0, stream>>>(hid, bc1);
    final_kernel<<<(NP + 3) / 4, 256, 0, stream>>>(hid, Wc2, bc2, out);
}

// Round 2
// 824.984 us; speedup vs baseline: 1.1642x; 1.1642x over previous
//
#include <hip/hip_runtime.h>
#include <hip/hip_bf16.h>
#include <math.h>

#define NN 100000   // nodes
#define NE 300000   // edges per snapshot
#define NS 5        // snapshots
#define DIN 128
#define HID 256
#define NP 10000    // post nodes

typedef short s8v __attribute__((ext_vector_type(8)));   // 8 x bf16 (guide-verified MFMA frag type)
typedef float f4v __attribute__((ext_vector_type(4)));

static __device__ __forceinline__ float bf2f(unsigned short u) {
    union { unsigned int i; float f; } v; v.i = ((unsigned int)u) << 16; return v.f;
}
static __device__ __forceinline__ unsigned short f2bf(float f) {
    union { float f; unsigned int i; } v; v.f = f;
    unsigned int i = v.i;
    return (unsigned short)((i + 0x7fff + ((i >> 16) & 1)) >> 16);   // RNE
}

// ---------------- CSR build ----------------

__global__ void count_kernel(const int* __restrict__ dst, int* __restrict__ cnt) {
    int i = blockIdx.x * blockDim.x + threadIdx.x;
    if (i < NE) atomicAdd(&cnt[dst[i]], 1);
}

__global__ void scan1_kernel(const int* __restrict__ cnt, int* __restrict__ offs,
                             int* __restrict__ bsum, int n) {
    __shared__ int s[256];
    int i = blockIdx.x * 256 + threadIdx.x;
    int v = (i < n) ? cnt[i] : 0;
    s[threadIdx.x] = v;
    __syncthreads();
    for (int d = 1; d < 256; d <<= 1) {
        int t = (threadIdx.x >= d) ? s[threadIdx.x - d] : 0;
        __syncthreads();
        s[threadIdx.x] += t;
        __syncthreads();
    }
    if (i < n) offs[i] = s[threadIdx.x] - v;
    if (threadIdx.x == 255) bsum[blockIdx.x] = s[255];
}

__global__ void scan2_kernel(int* __restrict__ bsum, int nb) {
    __shared__ int s[512];
    int i = threadIdx.x;
    int v = (i < nb) ? bsum[i] : 0;
    s[i] = v;
    __syncthreads();
    for (int d = 1; d < 512; d <<= 1) {
        int t = (i >= d) ? s[i - d] : 0;
        __syncthreads();
        s[i] += t;
        __syncthreads();
    }
    if (i < nb) bsum[i] = s[i] - v;
}

__global__ void scan3_kernel(int* __restrict__ offs, const int* __restrict__ bsum,
                             int* __restrict__ cursor, int n) {
    int i = blockIdx.x * 256 + threadIdx.x;
    if (i < n) {
        int o = offs[i] + bsum[blockIdx.x];
        offs[i] = o;
        cursor[i] = o;
    }
}

__global__ void dinv_kernel(const int* __restrict__ cnt, float* __restrict__ dinv, int n) {
    int i = blockIdx.x * blockDim.x + threadIdx.x;
    if (i < n) dinv[i] = rsqrtf((float)(cnt[i] + 1));
}

__global__ void fill_kernel(const int* __restrict__ src, const int* __restrict__ dst,
                            int* __restrict__ cursor, int* __restrict__ csr) {
    int i = blockIdx.x * blockDim.x + threadIdx.x;
    if (i < NE) {
        int d = dst[i];
        int pos = atomicAdd(&cursor[d], 1);
        csr[pos] = src[i];
    }
}

// ---------------- dtype prep ----------------

__global__ void cvt_kernel(const float* __restrict__ src, unsigned short* __restrict__ dstp, int n4) {
    int i = blockIdx.x * 256 + threadIdx.x;
    if (i < n4) {
        float4 v = *(const float4*)&src[(size_t)i * 4];
        ushort4 o;
        o.x = f2bf(v.x); o.y = f2bf(v.y); o.z = f2bf(v.z); o.w = f2bf(v.w);
        *(ushort4*)&dstp[(size_t)i * 4] = o;
    }
}

// W [K,Ncols] f32 -> Wt [Ncols,K] bf16
__global__ void tw_kernel(const float* __restrict__ W, unsigned short* __restrict__ Wt,
                          int K, int Ncols) {
    int i = blockIdx.x * 256 + threadIdx.x;
    if (i < K * Ncols) {
        int n = i / K, k = i - n * K;
        Wt[i] = f2bf(W[(size_t)k * Ncols + n]);
    }
}

// ---------------- aggregation in input space (128-dim, bf16) ----------------
// aggX[i,:] = sum_{src in in(i)} dinv[src]*Xb[src,:] + dinv[i]*Xb[i,:]

__global__ void aggX_kernel(const unsigned short* __restrict__ Xb, const float* __restrict__ dinv,
                            const int* __restrict__ offs, const int* __restrict__ cnt,
                            const int* __restrict__ csr, unsigned short* __restrict__ aggX) {
    int wave = threadIdx.x >> 6;
    int lane = threadIdx.x & 63;
    int node = blockIdx.x * 4 + wave;
    if (node >= NN) return;
    int o = offs[node], c = cnt[node];
    float di = dinv[node];
    float a0 = 0.f, a1 = 0.f;
    for (int k = 0; k < c; k++) {
        int s = csr[o + k];
        float w = dinv[s];
        unsigned int u = *(const unsigned int*)&Xb[(size_t)s * DIN + lane * 2];
        a0 += w * bf2f((unsigned short)(u & 0xffffu));
        a1 += w * bf2f((unsigned short)(u >> 16));
    }
    unsigned int us = *(const unsigned int*)&Xb[(size_t)node * DIN + lane * 2];
    a0 += di * bf2f((unsigned short)(us & 0xffffu));
    a1 += di * bf2f((unsigned short)(us >> 16));
    unsigned int ov = (unsigned int)f2bf(a0) | ((unsigned int)f2bf(a1) << 16);
    *(unsigned int*)&aggX[(size_t)node * DIN + lane * 2] = ov;
}

// ---------------- unified MFMA GEMM, 64 rows x 128 cols per block ----------------
// C = A[M,K]bf16 @ Bt^T, Bt stored [Ntot,K] bf16 (row = output col).
// EPI 1: x1 = relu(dinv[row]*acc + bias[col])            -> bf16, stride ostride
// EPI 2: aggP[row,col] += dinv[post[row]]*acc + bias[col] + bf2f(x1[post[row],col])
// EPI 3: out = relu(alpha*acc + bias[col])               -> f32

template<int K, int EPI>
__global__ void mfma_kernel(const unsigned short* __restrict__ A,
                            const unsigned short* __restrict__ Bt,
                            int M, int ostride,
                            const float* __restrict__ dinv,
                            const int* __restrict__ post,
                            const float* __restrict__ bias,
                            const unsigned short* __restrict__ x1,
                            float alpha,
                            void* __restrict__ OutP) {
    __shared__ unsigned short lds[128 * (K + 8)];
    int tid = threadIdx.x;
    int colbase = blockIdx.y * 128;
    // stage Bt tile transposed-row-major: lds[n][k], row stride K+8 (2-way banks, free)
    for (int t = tid; t < 128 * K / 4; t += 256) {
        int n = t / (K / 4);
        int k4 = (t - n * (K / 4)) * 4;
        *(ushort4*)&lds[n * (K + 8) + k4] = *(const ushort4*)&Bt[(size_t)(colbase + n) * K + k4];
    }
    __syncthreads();

    int wave = tid >> 6, lane = tid & 63, lr = lane & 15, g = lane >> 4;
    int rowbase = blockIdx.x * 64 + wave * 16;
    int arow = rowbase + lr;

    f4v acc[8];
    #pragma unroll
    for (int t = 0; t < 8; t++) acc[t] = (f4v){0.f, 0.f, 0.f, 0.f};

    #pragma unroll
    for (int kk = 0; kk < K / 32; kk++) {
        s8v a = (s8v){0, 0, 0, 0, 0, 0, 0, 0};
        if (arow < M) a = *(const s8v*)&A[(size_t)arow * K + kk * 32 + g * 8];
        #pragma unroll
        for (int t = 0; t < 8; t++) {
            s8v b = *(const s8v*)&lds[(t * 16 + lr) * (K + 8) + kk * 32 + g * 8];
            acc[t] = __builtin_amdgcn_mfma_f32_16x16x32_bf16(a, b, acc[t], 0, 0, 0);
        }
    }

    int orow0 = rowbase + g * 4;
    if (EPI == 1) {
        unsigned short* Out = (unsigned short*)OutP;
        #pragma unroll
        for (int r = 0; r < 4; r++) {
            int row = orow0 + r;
            if (row < M) {
                float sc = dinv[row];
                #pragma unroll
                for (int t = 0; t < 8; t++) {
                    int col = colbase + t * 16 + lr;
                    float v = sc * acc[t][r] + bias[col];
                    Out[(size_t)row * ostride + col] = f2bf(v > 0.f ? v : 0.f);
                }
            }
        }
    } else if (EPI == 2) {
        float* Out = (float*)OutP;
        #pragma unroll
        for (int r = 0; r < 4; r++) {
            int row = orow0 + r;
            if (row < M) {
                int nd = post[row];
                float sc = dinv[nd];
                #pragma unroll
                for (int t = 0; t < 8; t++) {
                    int col = colbase + t * 16 + lr;
                    Out[(size_t)row * ostride + col] +=
                        sc * acc[t][r] + bias[col] + bf2f(x1[(size_t)nd * HID + col]);
                }
            }
        }
    } else {
        float* Out = (float*)OutP;
        #pragma unroll
        for (int r = 0; r < 4; r++) {
            int row = orow0 + r;
            if (row < M) {
                #pragma unroll
                for (int t = 0; t < 8; t++) {
                    int col = colbase + t * 16 + lr;
                    float v = alpha * acc[t][r] + bias[col];
                    Out[(size_t)row * ostride + col] = v > 0.f ? v : 0.f;
                }
            }
        }
    }
}

// ---------------- layer-2 pre-aggregation at post slots (bf16 in/out, f32 accum) ----------------

__global__ void z2_kernel(const unsigned short* __restrict__ x1, const float* __restrict__ dinv,
                          const int* __restrict__ offs, const int* __restrict__ cnt,
                          const int* __restrict__ csr, const int* __restrict__ post,
                          unsigned short* __restrict__ z2b) {
    int wave = threadIdx.x >> 6;
    int lane = threadIdx.x & 63;
    int p = blockIdx.x * 4 + wave;
    if (p >= NP) return;
    int node = post[p];
    int o = offs[node], c = cnt[node];
    float di = dinv[node];
    float a0 = 0.f, a1 = 0.f, a2 = 0.f, a3 = 0.f;
    for (int k = 0; k < c; k++) {
        int s = csr[o + k];
        float w = dinv[s];
        ushort4 h = *(const ushort4*)&x1[(size_t)s * HID + lane * 4];
        a0 += w * bf2f(h.x); a1 += w * bf2f(h.y); a2 += w * bf2f(h.z); a3 += w * bf2f(h.w);
    }
    ushort4 hs = *(const ushort4*)&x1[(size_t)node * HID + lane * 4];
    a0 += di * bf2f(hs.x); a1 += di * bf2f(hs.y); a2 += di * bf2f(hs.z); a3 += di * bf2f(hs.w);
    ushort4 ov;
    ov.x = f2bf(a0); ov.y = f2bf(a1); ov.z = f2bf(a2); ov.w = f2bf(a3);
    *(ushort4*)&z2b[(size_t)p * HID + lane * 4] = ov;
}

// out[p] = sigmoid(hid[p,:] . Wc2 + bc2)
__global__ void final_kernel(const float* __restrict__ hid, const float* __restrict__ Wc2,
                             const float* __restrict__ bc2, float* __restrict__ out) {
    int wave = threadIdx.x >> 6;
    int lane = threadIdx.x & 63;
    int p = blockIdx.x * 4 + wave;
    if (p >= NP) return;
    float part = hid[(size_t)p * 128 + lane] * Wc2[lane]
               + hid[(size_t)p * 128 + 64 + lane] * Wc2[64 + lane];
    for (int off = 32; off; off >>= 1) part += __shfl_down(part, off, 64);
    if (lane == 0) out[p] = 1.f / (1.f + expf(-(part + bc2[0])));
}

// ---------------- host ----------------

extern "C" void kernel_launch(void* const* d_in, const int* in_sizes, int n_in,
                              void* d_out, int out_size, void* d_ws, size_t ws_size,
                              hipStream_t stream) {
    const float* X    = (const float*)d_in[0];
    const int*   EI   = (const int*)d_in[1];
    const int*   post = (const int*)d_in[2];
    const float* W1   = (const float*)d_in[3];
    const float* b1   = (const float*)d_in[4];
    const float* W2   = (const float*)d_in[5];
    const float* b2   = (const float*)d_in[6];
    const float* Wc1  = (const float*)d_in[7];
    const float* bc1  = (const float*)d_in[8];
    const float* Wc2  = (const float*)d_in[9];
    const float* bc2  = (const float*)d_in[10];
    float* out = (float*)d_out;

    char* w = (char*)d_ws;
    auto carve = [&](size_t bytes) {
        void* p = (void*)w;
        w += (bytes + 255) & ~(size_t)255;
        return p;
    };
    unsigned short* Xb   = (unsigned short*)carve((size_t)NN * DIN * 2);   // 25.6 MB
    unsigned short* aggX = (unsigned short*)carve((size_t)NN * DIN * 2);   // 25.6 MB
    unsigned short* x1   = (unsigned short*)carve((size_t)NN * HID * 2);   // 51.2 MB
    unsigned short* z2b  = (unsigned short*)carve((size_t)NP * HID * 2);   // 5.1 MB
    float* aggP          = (float*)carve((size_t)NP * HID * 4);            // 10.2 MB
    unsigned short* aggPb= (unsigned short*)carve((size_t)NP * HID * 2);   // 5.1 MB
    float* hid           = (float*)carve((size_t)NP * 128 * 4);            // 5.1 MB
    unsigned short* W1t  = (unsigned short*)carve((size_t)256 * 128 * 2);
    unsigned short* W2t  = (unsigned short*)carve((size_t)256 * 256 * 2);
    unsigned short* Wc1t = (unsigned short*)carve((size_t)128 * 256 * 2);
    float* dinv          = (float*)carve((size_t)NN * 4);
    int*   cnt           = (int*)carve((size_t)NN * 4);
    int*   offs          = (int*)carve((size_t)NN * 4);
    int*   cursor        = (int*)carve((size_t)NN * 4);
    int*   bsum          = (int*)carve(1024 * 4);
    int*   csr           = (int*)carve((size_t)NE * 4);

    const int NB_N = (NN + 255) / 256;   // 391

    hipMemsetAsync(aggP, 0, (size_t)NP * HID * 4, stream);
    cvt_kernel<<<(NN * DIN / 4 + 255) / 256, 256, 0, stream>>>(X, Xb, NN * DIN / 4);
    tw_kernel<<<(128 * 256 + 255) / 256, 256, 0, stream>>>(W1, W1t, 128, 256);
    tw_kernel<<<(256 * 256 + 255) / 256, 256, 0, stream>>>(W2, W2t, 256, 256);
    tw_kernel<<<(256 * 128 + 255) / 256, 256, 0, stream>>>(Wc1, Wc1t, 256, 128);

    for (int s = 0; s < NS; s++) {
        const int* src = EI + (size_t)s * 2 * NE;
        const int* dst = src + NE;

        hipMemsetAsync(cnt, 0, (size_t)NN * 4, stream);
        count_kernel<<<(NE + 255) / 256, 256, 0, stream>>>(dst, cnt);
        scan1_kernel<<<NB_N, 256, 0, stream>>>(cnt, offs, bsum, NN);
        scan2_kernel<<<1, 512, 0, stream>>>(bsum, NB_N);
        scan3_kernel<<<NB_N, 256, 0, stream>>>(offs, bsum, cursor, NN);
        dinv_kernel<<<NB_N, 256, 0, stream>>>(cnt, dinv, NN);
        fill_kernel<<<(NE + 255) / 256, 256, 0, stream>>>(src, dst, cursor, csr);

        aggX_kernel<<<(NN + 3) / 4, 256, 0, stream>>>(Xb, dinv, offs, cnt, csr, aggX);
        {
            dim3 g((NN + 63) / 64, 2);
            mfma_kernel<DIN, 1><<<g, 256, 0, stream>>>(aggX, W1t, NN, HID, dinv, nullptr,
                                                       b1, nullptr, 0.f, x1);
        }
        z2_kernel<<<(NP + 3) / 4, 256, 0, stream>>>(x1, dinv, offs, cnt, csr, post, z2b);
        {
            dim3 g((NP + 63) / 64, 2);
            mfma_kernel<HID, 2><<<g, 256, 0, stream>>>(z2b, W2t, NP, HID, dinv, post,
                                                       b2, x1, 0.f, aggP);
        }
    }

    cvt_kernel<<<(NP * HID / 4 + 255) / 256, 256, 0, stream>>>(aggP, aggPb, NP * HID / 4);
    {
        dim3 g((NP + 63) / 64, 1);
        mfma_kernel<HID, 3><<<g, 256, 0, stream>>>(aggPb, Wc1t, NP, 128, nullptr, nullptr,
                                                   bc1, nullptr, 0.2f, hid);
    }
    final_kernel<<<(NP + 3) / 4, 256, 0, stream>>>(hid, Wc2, bc2, out);
}

// Round 3
// 528.926 us; speedup vs baseline: 1.8158x; 1.5597x over previous
//
#include <hip/hip_runtime.h>
#include <hip/hip_bf16.h>
#include <math.h>

#define NN 100000   // nodes
#define NE 300000   // edges per snapshot
#define NS 5        // snapshots
#define DIN 128
#define HID 256
#define NP 10000    // post nodes
#define NB_N 391    // ceil(NN/256)

typedef short s8v __attribute__((ext_vector_type(8)));   // 8 x bf16
typedef float f4v __attribute__((ext_vector_type(4)));

static __device__ __forceinline__ float bf2f(unsigned short u) {
    union { unsigned int i; float f; } v; v.i = ((unsigned int)u) << 16; return v.f;
}
static __device__ __forceinline__ unsigned short f2bf(float f) {
    union { float f; unsigned int i; } v; v.f = f;
    return (unsigned short)((v.i + 0x7fff + ((v.i >> 16) & 1)) >> 16);   // RNE
}

// ---------------- marking / CSR build (all 5 snapshots batched, grid.y = s) ----------------

__global__ void setpost_kernel(const int* __restrict__ post, int* __restrict__ isPost) {
    int i = blockIdx.x * 256 + threadIdx.x;
    if (i < NP) isPost[post[i]] = 1;
}

__global__ void markpost_kernel(const int* __restrict__ post, int* __restrict__ needed) {
    int i = blockIdx.x * 256 + threadIdx.x;
    int s = blockIdx.y;
    if (i < NP) needed[(size_t)s * NN + post[i]] = 1;
}

// count in-degree + mark srcs of edges that land on post nodes
__global__ void count_mark_kernel(const int* __restrict__ EI, const int* __restrict__ isPost,
                                  int* __restrict__ cnt, int* __restrict__ needed) {
    int i = blockIdx.x * 256 + threadIdx.x;
    int s = blockIdx.y;
    if (i < NE) {
        const int* srcp = EI + (size_t)s * 2 * NE;
        int sv = srcp[i], d = srcp[NE + i];
        atomicAdd(&cnt[(size_t)s * NN + d], 1);
        if (isPost[d]) needed[(size_t)s * NN + sv] = 1;
    }
}

__global__ void scan1_kernel(const int* __restrict__ in, int* __restrict__ offs,
                             int* __restrict__ bsum) {
    __shared__ int sm[256];
    int s = blockIdx.y;
    int i = blockIdx.x * 256 + threadIdx.x;
    int tid = threadIdx.x;
    int v = (i < NN) ? in[(size_t)s * NN + i] : 0;
    sm[tid] = v;
    __syncthreads();
    for (int d = 1; d < 256; d <<= 1) {
        int t = (tid >= d) ? sm[tid - d] : 0;
        __syncthreads();
        sm[tid] += t;
        __syncthreads();
    }
    if (i < NN) offs[(size_t)s * NN + i] = sm[tid] - v;   // exclusive within block
    if (tid == 255) bsum[s * 512 + blockIdx.x] = sm[255];
}

__global__ void scan2_kernel(int* __restrict__ bsum, int* __restrict__ total) {
    __shared__ int sm[512];
    int s = blockIdx.x;
    int i = threadIdx.x;
    int v = (i < NB_N) ? bsum[s * 512 + i] : 0;
    sm[i] = v;
    __syncthreads();
    for (int d = 1; d < 512; d <<= 1) {
        int t = (i >= d) ? sm[i - d] : 0;
        __syncthreads();
        sm[i] += t;
        __syncthreads();
    }
    if (i < NB_N) bsum[s * 512 + i] = sm[i] - v;          // exclusive
    if (total != nullptr && i == NB_N - 1) total[s] = sm[i];  // inclusive total
}

__global__ void csr_scan3_kernel(int* __restrict__ offs, const int* __restrict__ bsum,
                                 int* __restrict__ cursor, const int* __restrict__ cnt,
                                 float* __restrict__ dinv) {
    int s = blockIdx.y;
    int i = blockIdx.x * 256 + threadIdx.x;
    if (i < NN) {
        size_t idx = (size_t)s * NN + i;
        int o = offs[idx] + bsum[s * 512 + blockIdx.x];
        offs[idx] = o;
        cursor[idx] = o;
        dinv[idx] = rsqrtf((float)(cnt[idx] + 1));   // +1 self loop
    }
}

__global__ void cmp_scan3_kernel(const int* __restrict__ noffs, const int* __restrict__ bsum,
                                 const int* __restrict__ needed, int* __restrict__ list,
                                 int* __restrict__ inv) {
    int s = blockIdx.y;
    int i = blockIdx.x * 256 + threadIdx.x;
    if (i < NN) {
        size_t idx = (size_t)s * NN + i;
        if (needed[idx]) {
            int slot = noffs[idx] + bsum[s * 512 + blockIdx.x];
            list[(size_t)s * NN + slot] = i;
            inv[idx] = slot;
        }
    }
}

__global__ void fill_kernel(const int* __restrict__ EI, int* __restrict__ cursor,
                            int* __restrict__ csr) {
    int i = blockIdx.x * 256 + threadIdx.x;
    int s = blockIdx.y;
    if (i < NE) {
        const int* srcp = EI + (size_t)s * 2 * NE;
        int sv = srcp[i], d = srcp[NE + i];
        int pos = atomicAdd(&cursor[(size_t)s * NN + d], 1);
        csr[(size_t)s * NE + pos] = sv;
    }
}

// ---------------- dtype prep ----------------

__global__ void cvt_kernel(const float* __restrict__ src, unsigned short* __restrict__ dstp, int n4) {
    int i = blockIdx.x * 256 + threadIdx.x;
    if (i < n4) {
        float4 v = *(const float4*)&src[(size_t)i * 4];
        ushort4 o;
        o.x = f2bf(v.x); o.y = f2bf(v.y); o.z = f2bf(v.z); o.w = f2bf(v.w);
        *(ushort4*)&dstp[(size_t)i * 4] = o;
    }
}

// W [K,Ncols] f32 -> Wt [Ncols,K] bf16
__global__ void tw_kernel(const float* __restrict__ W, unsigned short* __restrict__ Wt,
                          int K, int Ncols) {
    int i = blockIdx.x * 256 + threadIdx.x;
    if (i < K * Ncols) {
        int n = i / K, k = i - n * K;
        Wt[i] = f2bf(W[(size_t)k * Ncols + n]);
    }
}

// ---------------- aggX over compacted needed-list, 4-edge ILP ----------------
// aggXc[slot,:] = sum_{src in in(list[slot])} dinv[src]*Xb[src,:] + dinv[node]*Xb[node,:]
// 4 edge-groups of 16 lanes; each lane covers 8 of 128 cols (16B).

__global__ void aggX_kernel(const unsigned short* __restrict__ Xb, const float* __restrict__ dinv,
                            const int* __restrict__ offs, const int* __restrict__ cnt,
                            const int* __restrict__ csr, const int* __restrict__ list,
                            const int* __restrict__ ncount,
                            unsigned short* __restrict__ aggXc) {
    int wave = threadIdx.x >> 6, lane = threadIdx.x & 63;
    int eg = lane >> 4, el = lane & 15;
    int ncnt = ncount[0];
    for (int slot = blockIdx.x * 4 + wave; slot < ncnt; slot += gridDim.x * 4) {
        int node = list[slot];
        int o = offs[node], c = cnt[node];
        float acc[8] = {0.f, 0.f, 0.f, 0.f, 0.f, 0.f, 0.f, 0.f};
        for (int k = eg; k < c; k += 4) {
            int sv = csr[o + k];
            float wgt = dinv[sv];
            s8v h = *(const s8v*)&Xb[(size_t)sv * DIN + el * 8];
            #pragma unroll
            for (int j = 0; j < 8; j++) acc[j] += wgt * bf2f((unsigned short)h[j]);
        }
        if (eg == 0) {
            float di = dinv[node];
            s8v h = *(const s8v*)&Xb[(size_t)node * DIN + el * 8];
            #pragma unroll
            for (int j = 0; j < 8; j++) acc[j] += di * bf2f((unsigned short)h[j]);
        }
        #pragma unroll
        for (int j = 0; j < 8; j++) {
            acc[j] += __shfl_xor(acc[j], 16, 64);
            acc[j] += __shfl_xor(acc[j], 32, 64);
        }
        if (eg == 0) {
            s8v o8;
            #pragma unroll
            for (int j = 0; j < 8; j++) o8[j] = (short)f2bf(acc[j]);
            *(s8v*)&aggXc[(size_t)slot * DIN + el * 8] = o8;
        }
    }
}

// ---------------- layer-2 pre-aggregation at post slots, 4-edge ILP ----------------
// x1 rows are compacted; lookup via inv[]. 16 lanes x 32B cover the 512B row.

__global__ void z2_kernel(const unsigned short* __restrict__ x1c, const float* __restrict__ dinv,
                          const int* __restrict__ offs, const int* __restrict__ cnt,
                          const int* __restrict__ csr, const int* __restrict__ inv,
                          const int* __restrict__ post, unsigned short* __restrict__ z2b) {
    int wave = threadIdx.x >> 6, lane = threadIdx.x & 63;
    int eg = lane >> 4, el = lane & 15;
    int p = blockIdx.x * 4 + wave;
    if (p >= NP) return;
    int node = post[p];
    int o = offs[node], c = cnt[node];
    float acc0[8] = {0.f, 0.f, 0.f, 0.f, 0.f, 0.f, 0.f, 0.f};
    float acc1[8] = {0.f, 0.f, 0.f, 0.f, 0.f, 0.f, 0.f, 0.f};
    for (int k = eg; k < c; k += 4) {
        int sv = csr[o + k];
        float wgt = dinv[sv];
        int r = inv[sv];
        const unsigned short* rp = &x1c[(size_t)r * HID + el * 16];
        s8v h0 = *(const s8v*)rp;
        s8v h1 = *(const s8v*)(rp + 8);
        #pragma unroll
        for (int j = 0; j < 8; j++) {
            acc0[j] += wgt * bf2f((unsigned short)h0[j]);
            acc1[j] += wgt * bf2f((unsigned short)h1[j]);
        }
    }
    if (eg == 0) {
        float di = dinv[node];
        int r = inv[node];
        const unsigned short* rp = &x1c[(size_t)r * HID + el * 16];
        s8v h0 = *(const s8v*)rp;
        s8v h1 = *(const s8v*)(rp + 8);
        #pragma unroll
        for (int j = 0; j < 8; j++) {
            acc0[j] += di * bf2f((unsigned short)h0[j]);
            acc1[j] += di * bf2f((unsigned short)h1[j]);
        }
    }
    #pragma unroll
    for (int j = 0; j < 8; j++) {
        acc0[j] += __shfl_xor(acc0[j], 16, 64);
        acc0[j] += __shfl_xor(acc0[j], 32, 64);
        acc1[j] += __shfl_xor(acc1[j], 16, 64);
        acc1[j] += __shfl_xor(acc1[j], 32, 64);
    }
    if (eg == 0) {
        s8v o0, o1;
        #pragma unroll
        for (int j = 0; j < 8; j++) {
            o0[j] = (short)f2bf(acc0[j]);
            o1[j] = (short)f2bf(acc1[j]);
        }
        unsigned short* wp = &z2b[(size_t)p * HID + el * 16];
        *(s8v*)wp = o0;
        *(s8v*)(wp + 8) = o1;
    }
}

// ---------------- unified MFMA GEMM, 64 rows x 128 cols per block ----------------
// C = A[M,K]bf16 @ Bt^T, Bt stored [Ntot,K] bf16 (row = output col). M may be dynamic (Mptr).
// EPI 1: x1c[row] = relu(dinv[rowmap[row]]*acc + bias[col])           -> bf16
// EPI 2: aggP[row,col] += dinv[nd]*acc + bias[col] + x1c[inv[nd],col], nd=rowmap[row]
// EPI 3: out = relu(alpha*acc + bias[col])                            -> f32

template<int K, int EPI>
__global__ void mfma_kernel(const unsigned short* __restrict__ A,
                            const unsigned short* __restrict__ Bt,
                            int Mfixed, const int* __restrict__ Mptr, int ostride,
                            const float* __restrict__ dinv,
                            const int* __restrict__ rowmap,
                            const int* __restrict__ invmap,
                            const float* __restrict__ bias,
                            const unsigned short* __restrict__ x1,
                            float alpha,
                            void* __restrict__ OutP) {
    int M = Mptr ? *Mptr : Mfixed;
    if (blockIdx.x * 64 >= M) return;

    __shared__ unsigned short lds[128 * (K + 8)];
    int tid = threadIdx.x;
    int colbase = blockIdx.y * 128;
    for (int t = tid; t < 128 * K / 4; t += 256) {
        int n = t / (K / 4);
        int k4 = (t - n * (K / 4)) * 4;
        *(ushort4*)&lds[n * (K + 8) + k4] = *(const ushort4*)&Bt[(size_t)(colbase + n) * K + k4];
    }
    __syncthreads();

    int wave = tid >> 6, lane = tid & 63, lr = lane & 15, g = lane >> 4;
    int rowbase = blockIdx.x * 64 + wave * 16;
    int arow = rowbase + lr;

    f4v acc[8];
    #pragma unroll
    for (int t = 0; t < 8; t++) acc[t] = (f4v){0.f, 0.f, 0.f, 0.f};

    #pragma unroll
    for (int kk = 0; kk < K / 32; kk++) {
        s8v a = (s8v){0, 0, 0, 0, 0, 0, 0, 0};
        if (arow < M) a = *(const s8v*)&A[(size_t)arow * K + kk * 32 + g * 8];
        #pragma unroll
        for (int t = 0; t < 8; t++) {
            s8v b = *(const s8v*)&lds[(t * 16 + lr) * (K + 8) + kk * 32 + g * 8];
            acc[t] = __builtin_amdgcn_mfma_f32_16x16x32_bf16(a, b, acc[t], 0, 0, 0);
        }
    }

    int orow0 = rowbase + g * 4;
    if (EPI == 1) {
        unsigned short* Out = (unsigned short*)OutP;
        #pragma unroll
        for (int r = 0; r < 4; r++) {
            int row = orow0 + r;
            if (row < M) {
                float sc = dinv[rowmap[row]];
                #pragma unroll
                for (int t = 0; t < 8; t++) {
                    int col = colbase + t * 16 + lr;
                    float v = sc * acc[t][r] + bias[col];
                    Out[(size_t)row * ostride + col] = f2bf(v > 0.f ? v : 0.f);
                }
            }
        }
    } else if (EPI == 2) {
        float* Out = (float*)OutP;
        #pragma unroll
        for (int r = 0; r < 4; r++) {
            int row = orow0 + r;
            if (row < M) {
                int nd = rowmap[row];
                float sc = dinv[nd];
                size_t x1row = (size_t)invmap[nd] * HID;
                #pragma unroll
                for (int t = 0; t < 8; t++) {
                    int col = colbase + t * 16 + lr;
                    Out[(size_t)row * ostride + col] +=
                        sc * acc[t][r] + bias[col] + bf2f(x1[x1row + col]);
                }
            }
        }
    } else {
        float* Out = (float*)OutP;
        #pragma unroll
        for (int r = 0; r < 4; r++) {
            int row = orow0 + r;
            if (row < M) {
                #pragma unroll
                for (int t = 0; t < 8; t++) {
                    int col = colbase + t * 16 + lr;
                    float v = alpha * acc[t][r] + bias[col];
                    Out[(size_t)row * ostride + col] = v > 0.f ? v : 0.f;
                }
            }
        }
    }
}

// out[p] = sigmoid(hid[p,:] . Wc2 + bc2)
__global__ void final_kernel(const float* __restrict__ hid, const float* __restrict__ Wc2,
                             const float* __restrict__ bc2, float* __restrict__ out) {
    int wave = threadIdx.x >> 6;
    int lane = threadIdx.x & 63;
    int p = blockIdx.x * 4 + wave;
    if (p >= NP) return;
    float part = hid[(size_t)p * 128 + lane] * Wc2[lane]
               + hid[(size_t)p * 128 + 64 + lane] * Wc2[64 + lane];
    for (int off = 32; off; off >>= 1) part += __shfl_down(part, off, 64);
    if (lane == 0) out[p] = 1.f / (1.f + expf(-(part + bc2[0])));
}

// ---------------- host ----------------

extern "C" void kernel_launch(void* const* d_in, const int* in_sizes, int n_in,
                              void* d_out, int out_size, void* d_ws, size_t ws_size,
                              hipStream_t stream) {
    const float* X    = (const float*)d_in[0];
    const int*   EI   = (const int*)d_in[1];
    const int*   post = (const int*)d_in[2];
    const float* W1   = (const float*)d_in[3];
    const float* b1   = (const float*)d_in[4];
    const float* W2   = (const float*)d_in[5];
    const float* b2   = (const float*)d_in[6];
    const float* Wc1  = (const float*)d_in[7];
    const float* bc1  = (const float*)d_in[8];
    const float* Wc2  = (const float*)d_in[9];
    const float* bc2  = (const float*)d_in[10];
    float* out = (float*)d_out;

    char* w = (char*)d_ws;
    auto carve = [&](size_t bytes) {
        void* p = (void*)w;
        w += (bytes + 255) & ~(size_t)255;
        return p;
    };
    unsigned short* Xb    = (unsigned short*)carve((size_t)NN * DIN * 2);   // 25.6 MB
    unsigned short* aggXc = (unsigned short*)carve((size_t)NN * DIN * 2);   // 25.6 MB (reused /snapshot)
    unsigned short* x1c   = (unsigned short*)carve((size_t)NN * HID * 2);   // 51.2 MB (reused /snapshot)
    unsigned short* z2b   = (unsigned short*)carve((size_t)NP * HID * 2);   // 5.1 MB
    float* aggP           = (float*)carve((size_t)NP * HID * 4);            // 10.2 MB
    unsigned short* aggPb = (unsigned short*)carve((size_t)NP * HID * 2);   // 5.1 MB
    float* hid            = (float*)carve((size_t)NP * 128 * 4);            // 5.1 MB
    unsigned short* W1t   = (unsigned short*)carve((size_t)256 * 128 * 2);
    unsigned short* W2t   = (unsigned short*)carve((size_t)256 * 256 * 2);
    unsigned short* Wc1t  = (unsigned short*)carve((size_t)128 * 256 * 2);
    float* dinv           = (float*)carve((size_t)NS * NN * 4);             // 2 MB
    int*   cnt            = (int*)carve((size_t)NS * NN * 4);
    int*   offs           = (int*)carve((size_t)NS * NN * 4);
    int*   cursor         = (int*)carve((size_t)NS * NN * 4);
    int*   needed         = (int*)carve((size_t)NS * NN * 4);
    int*   noffs          = (int*)carve((size_t)NS * NN * 4);
    int*   list           = (int*)carve((size_t)NS * NN * 4);
    int*   inv            = (int*)carve((size_t)NS * NN * 4);
    int*   isPost         = (int*)carve((size_t)NN * 4);
    int*   bsum           = (int*)carve((size_t)NS * 512 * 4);
    int*   bsum2          = (int*)carve((size_t)NS * 512 * 4);
    int*   ncount         = (int*)carve((size_t)NS * 4);
    int*   csr            = (int*)carve((size_t)NS * NE * 4);               // 6 MB

    // ---- prep (one-time per call) ----
    hipMemsetAsync(aggP, 0, (size_t)NP * HID * 4, stream);
    hipMemsetAsync(cnt, 0, (size_t)NS * NN * 4, stream);
    hipMemsetAsync(needed, 0, (size_t)NS * NN * 4, stream);
    hipMemsetAsync(isPost, 0, (size_t)NN * 4, stream);
    cvt_kernel<<<(NN * DIN / 4 + 255) / 256, 256, 0, stream>>>(X, Xb, NN * DIN / 4);
    tw_kernel<<<(128 * 256 + 255) / 256, 256, 0, stream>>>(W1, W1t, 128, 256);
    tw_kernel<<<(256 * 256 + 255) / 256, 256, 0, stream>>>(W2, W2t, 256, 256);
    tw_kernel<<<(256 * 128 + 255) / 256, 256, 0, stream>>>(Wc1, Wc1t, 256, 128);
    setpost_kernel<<<(NP + 255) / 256, 256, 0, stream>>>(post, isPost);

    // ---- batched CSR build + needed-set compaction for all snapshots ----
    const int NB_E = (NE + 255) / 256;
    count_mark_kernel<<<dim3(NB_E, NS), 256, 0, stream>>>(EI, isPost, cnt, needed);
    markpost_kernel<<<dim3((NP + 255) / 256, NS), 256, 0, stream>>>(post, needed);
    scan1_kernel<<<dim3(NB_N, NS), 256, 0, stream>>>(cnt, offs, bsum);
    scan1_kernel<<<dim3(NB_N, NS), 256, 0, stream>>>(needed, noffs, bsum2);
    scan2_kernel<<<NS, 512, 0, stream>>>(bsum, nullptr);
    scan2_kernel<<<NS, 512, 0, stream>>>(bsum2, ncount);
    csr_scan3_kernel<<<dim3(NB_N, NS), 256, 0, stream>>>(offs, bsum, cursor, cnt, dinv);
    cmp_scan3_kernel<<<dim3(NB_N, NS), 256, 0, stream>>>(noffs, bsum2, needed, list, inv);
    fill_kernel<<<dim3(NB_E, NS), 256, 0, stream>>>(EI, cursor, csr);

    // ---- per-snapshot compute ----
    for (int s = 0; s < NS; s++) {
        const float* dinv_s = dinv + (size_t)s * NN;
        const int* offs_s   = offs + (size_t)s * NN;
        const int* cnt_s    = cnt + (size_t)s * NN;
        const int* csr_s    = csr + (size_t)s * NE;
        const int* list_s   = list + (size_t)s * NN;
        const int* inv_s    = inv + (size_t)s * NN;
        const int* ncnt_s   = ncount + s;

        aggX_kernel<<<8192, 256, 0, stream>>>(Xb, dinv_s, offs_s, cnt_s, csr_s,
                                              list_s, ncnt_s, aggXc);
        {
            dim3 g((NN + 63) / 64, 2);
            mfma_kernel<DIN, 1><<<g, 256, 0, stream>>>(aggXc, W1t, 0, ncnt_s, HID,
                                                       dinv_s, list_s, nullptr,
                                                       b1, nullptr, 0.f, x1c);
        }
        z2_kernel<<<(NP + 3) / 4, 256, 0, stream>>>(x1c, dinv_s, offs_s, cnt_s, csr_s,
                                                    inv_s, post, z2b);
        {
            dim3 g((NP + 63) / 64, 2);
            mfma_kernel<HID, 2><<<g, 256, 0, stream>>>(z2b, W2t, NP, nullptr, HID,
                                                       dinv_s, post, inv_s,
                                                       b2, x1c, 0.f, aggP);
        }
    }

    // ---- classifier ----
    cvt_kernel<<<(NP * HID / 4 + 255) / 256, 256, 0, stream>>>(aggP, aggPb, NP * HID / 4);
    {
        dim3 g((NP + 63) / 64, 1);
        mfma_kernel<HID, 3><<<g, 256, 0, stream>>>(aggPb, Wc1t, NP, nullptr, 128,
                                                   nullptr, nullptr, nullptr,
                                                   bc1, nullptr, 0.2f, hid);
    }
    final_kernel<<<(NP + 3) / 4, 256, 0, stream>>>(hid, Wc2, bc2, out);
}

// Round 4
// 453.480 us; speedup vs baseline: 2.1179x; 1.1664x over previous
//
#include <hip/hip_runtime.h>
#include <hip/hip_bf16.h>
#include <math.h>

#define NN 100000   // nodes
#define NE 300000   // edges per snapshot
#define NS 5        // snapshots
#define DIN 128
#define HID 256
#define NP 10000    // post nodes
#define NB_N 391    // ceil(NN/256)

#define NBUCK 1024      // bucket count (dst>>7), 782 used
#define NBUCK_USED 782
#define PBLK 64         // partition blocks per snapshot
#define EPB 19          // edges per thread: 64*256*19 >= NE
#define BCAP 2048       // max edges per bucket (mean 384, +38 sigma)

typedef short s8v __attribute__((ext_vector_type(8)));   // 8 x bf16
typedef float f4v __attribute__((ext_vector_type(4)));

static __device__ __forceinline__ float bf2f(unsigned short u) {
    union { unsigned int i; float f; } v; v.i = ((unsigned int)u) << 16; return v.f;
}
static __device__ __forceinline__ unsigned short f2bf(float f) {
    union { float f; unsigned int i; } v; v.f = f;
    return (unsigned short)((v.i + 0x7fff + ((v.i >> 16) & 1)) >> 16);   // RNE
}

// ---------------- post marking ----------------

__global__ void setpost_kernel(const int* __restrict__ post, int* __restrict__ isPost,
                               int* __restrict__ needed) {
    int i = blockIdx.x * 256 + threadIdx.x;
    int s = blockIdx.y;
    if (i < NP) {
        int nd = post[i];
        needed[(size_t)s * NN + nd] = 1;
        if (s == 0) isPost[nd] = 1;
    }
}

// ---------------- bucket-partition CSR build (dense writes, no global data atomics) ----

// per-snapshot bucket histogram
__global__ void hist_kernel(const int* __restrict__ EI, int* __restrict__ bhist) {
    __shared__ int h[NBUCK];
    int s = blockIdx.y, b = blockIdx.x, t = threadIdx.x;
    for (int q = t; q < NBUCK; q += 256) h[q] = 0;
    __syncthreads();
    const int* dstp = EI + (size_t)s * 2 * NE + NE;
    int e0 = b * (EPB * 256);
    #pragma unroll
    for (int j = 0; j < EPB; j++) {
        int e = e0 + j * 256 + t;
        if (e < NE) atomicAdd(&h[dstp[e] >> 7], 1);
    }
    __syncthreads();
    for (int q = t; q < NBUCK; q += 256)
        if (h[q]) atomicAdd(&bhist[s * NBUCK + q], h[q]);
}

// bucket bases (exclusive scan) per snapshot; init append cursors
__global__ void bscan_kernel(const int* __restrict__ bhist, int* __restrict__ bbase,
                             int* __restrict__ bcur) {
    __shared__ int sm[NBUCK];
    int s = blockIdx.x, t = threadIdx.x;
    int v = bhist[s * NBUCK + t];
    sm[t] = v;
    __syncthreads();
    for (int d = 1; d < NBUCK; d <<= 1) {
        int x = (t >= d) ? sm[t - d] : 0;
        __syncthreads();
        sm[t] += x;
        __syncthreads();
    }
    int base = sm[t] - v;
    bbase[s * NBUCK + t] = base;
    bcur[s * NBUCK + t] = base;
}

// partition edges into bucket-contiguous (src,dst) pairs; one atomic per (block,bucket)
__global__ void part_kernel(const int* __restrict__ EI, int* __restrict__ bcur,
                            int2* __restrict__ pairs) {
    __shared__ int h[NBUCK];
    __shared__ int base[NBUCK];
    int s = blockIdx.y, b = blockIdx.x, t = threadIdx.x;
    for (int q = t; q < NBUCK; q += 256) h[q] = 0;
    __syncthreads();
    const int* srcp = EI + (size_t)s * 2 * NE;
    const int* dstp = srcp + NE;
    int e0 = b * (EPB * 256);
    int rs[EPB], rd[EPB];
    #pragma unroll
    for (int j = 0; j < EPB; j++) {
        int e = e0 + j * 256 + t;
        if (e < NE) {
            rs[j] = srcp[e];
            rd[j] = dstp[e];
            atomicAdd(&h[rd[j] >> 7], 1);
        } else {
            rd[j] = -1; rs[j] = 0;
        }
    }
    __syncthreads();
    for (int q = t; q < NBUCK; q += 256) {
        int c = h[q];
        base[q] = c ? atomicAdd(&bcur[s * NBUCK + q], c) : 0;
    }
    __syncthreads();
    #pragma unroll
    for (int j = 0; j < EPB; j++) {
        if (rd[j] >= 0) {
            int pos = atomicAdd(&base[rd[j] >> 7], 1);
            pairs[(size_t)s * NE + pos] = make_int2(rs[j], rd[j]);
        }
    }
}

// per-bucket: node histogram + LDS scan -> cnt/offs/dinv/csr (all dense); mark needed srcs
__global__ void bucket_csr_kernel(const int2* __restrict__ pairs, const int* __restrict__ bbase,
                                  const int* __restrict__ bhist, const int* __restrict__ isPost,
                                  int* __restrict__ cnt, int* __restrict__ offs,
                                  float* __restrict__ dinv, int* __restrict__ csr,
                                  int* __restrict__ needed) {
    __shared__ int nh[128];
    __shared__ int noff[128];
    __shared__ int sbuf[BCAP];
    int s = blockIdx.y, b = blockIdx.x, t = threadIdx.x;
    int base = bbase[s * NBUCK + b];
    int count = bhist[s * NBUCK + b];
    if (count > BCAP) count = BCAP;   // statistically unreachable
    if (t < 128) nh[t] = 0;
    __syncthreads();
    const int2* pp = pairs + (size_t)s * NE + base;
    for (int e = t; e < count; e += 256)
        atomicAdd(&nh[pp[e].y & 127], 1);
    __syncthreads();
    if (t < 128) noff[t] = nh[t];
    __syncthreads();
    for (int d = 1; d < 128; d <<= 1) {
        int x = 0;
        if (t < 128 && t >= d) x = noff[t - d];
        __syncthreads();
        if (t < 128) noff[t] += x;
        __syncthreads();
    }
    if (t < 128) {
        int excl = noff[t] - nh[t];
        noff[t] = excl;
        int g = b * 128 + t;
        if (g < NN) {
            int c = nh[t];
            cnt[(size_t)s * NN + g]  = c;
            offs[(size_t)s * NN + g] = base + excl;
            dinv[(size_t)s * NN + g] = rsqrtf((float)(c + 1));   // +1 self loop
        }
    }
    __syncthreads();
    for (int e = t; e < count; e += 256) {
        int2 pr = pp[e];
        int pos = atomicAdd(&noff[pr.y & 127], 1);
        sbuf[pos] = pr.x;
        if (isPost[pr.y]) needed[(size_t)s * NN + pr.x] = 1;
    }
    __syncthreads();
    for (int e = t; e < count; e += 256)
        csr[(size_t)s * NE + base + e] = sbuf[e];
}

// ---------------- needed-set compaction (order irrelevant; consumers use inv) ------------

__global__ void compact_kernel(const int* __restrict__ needed, int* __restrict__ ncount,
                               int* __restrict__ list, int* __restrict__ inv) {
    int s = blockIdx.y;
    int i = blockIdx.x * 256 + threadIdx.x;
    if (i < NN && needed[(size_t)s * NN + i]) {
        int slot = atomicAdd(&ncount[s], 1);
        list[(size_t)s * NN + slot] = i;
        inv[(size_t)s * NN + i] = slot;
    }
}

// ---------------- dtype prep ----------------

__global__ void cvt_kernel(const float* __restrict__ src, unsigned short* __restrict__ dstp, int n4) {
    int i = blockIdx.x * 256 + threadIdx.x;
    if (i < n4) {
        float4 v = *(const float4*)&src[(size_t)i * 4];
        ushort4 o;
        o.x = f2bf(v.x); o.y = f2bf(v.y); o.z = f2bf(v.z); o.w = f2bf(v.w);
        *(ushort4*)&dstp[(size_t)i * 4] = o;
    }
}

// W [K,Ncols] f32 -> Wt [Ncols,K] bf16
__global__ void tw_kernel(const float* __restrict__ W, unsigned short* __restrict__ Wt,
                          int K, int Ncols) {
    int i = blockIdx.x * 256 + threadIdx.x;
    if (i < K * Ncols) {
        int n = i / K, k = i - n * K;
        Wt[i] = f2bf(W[(size_t)k * Ncols + n]);
    }
}

// ---------------- fused layer-1: register-gather aggregate + MFMA GEMM (K=128 -> 256) ---
// Each lane (g=lane>>4, lr=lane&15) gathers exactly its A-fragment columns
// {kk*32+g*8 .. +7} of row (rowbase+lr) over the row's in-edges, packs bf16, MFMA vs
// W1t staged in LDS. EPI: x1c[row] = relu(dinv[node]*acc + b1[col]).

__global__ __launch_bounds__(256) void agg_mm1_kernel(
        const unsigned short* __restrict__ Xb, const unsigned short* __restrict__ W1t,
        const int* __restrict__ Mptr, const float* __restrict__ dinv,
        const int* __restrict__ offs, const int* __restrict__ cnt,
        const int* __restrict__ csr, const int* __restrict__ list,
        const float* __restrict__ b1, unsigned short* __restrict__ x1c) {
    int M = *Mptr;
    if (blockIdx.x * 64 >= M) return;

    __shared__ unsigned short ldsB[256 * 136];   // [n][k], pad 8 -> 2-way banks (free)
    int tid = threadIdx.x;
    for (int q = tid; q < 256 * 16; q += 256) {   // 16 chunks of 8 shorts per row
        int n = q >> 4;
        int k8 = (q & 15) * 8;
        *(s8v*)&ldsB[n * 136 + k8] = *(const s8v*)&W1t[n * 128 + k8];
    }
    __syncthreads();

    int wave = tid >> 6, lane = tid & 63, lr = lane & 15, g = lane >> 4;
    int rowbase = blockIdx.x * 64 + wave * 16;
    int arow = rowbase + lr;

    float ga[4][8];
    #pragma unroll
    for (int kk = 0; kk < 4; kk++)
        #pragma unroll
        for (int j = 0; j < 8; j++) ga[kk][j] = 0.f;

    if (arow < M) {
        int node = list[arow];
        int o = offs[node], c = cnt[node];
        float di = dinv[node];
        const unsigned short* rp = Xb + (size_t)node * DIN + g * 8;
        #pragma unroll
        for (int kk = 0; kk < 4; kk++) {
            s8v h = *(const s8v*)(rp + kk * 32);
            #pragma unroll
            for (int j = 0; j < 8; j++) ga[kk][j] = di * bf2f((unsigned short)h[j]);
        }
        for (int k = 0; k < c; k++) {
            int sv = csr[o + k];
            float wgt = dinv[sv];
            const unsigned short* sp = Xb + (size_t)sv * DIN + g * 8;
            #pragma unroll
            for (int kk = 0; kk < 4; kk++) {
                s8v h = *(const s8v*)(sp + kk * 32);
                #pragma unroll
                for (int j = 0; j < 8; j++) ga[kk][j] += wgt * bf2f((unsigned short)h[j]);
            }
        }
    }

    s8v afr[4];
    #pragma unroll
    for (int kk = 0; kk < 4; kk++)
        #pragma unroll
        for (int j = 0; j < 8; j++) afr[kk][j] = (short)f2bf(ga[kk][j]);

    f4v acc[16];
    #pragma unroll
    for (int t8 = 0; t8 < 16; t8++) acc[t8] = (f4v){0.f, 0.f, 0.f, 0.f};
    #pragma unroll
    for (int kk = 0; kk < 4; kk++) {
        #pragma unroll
        for (int t8 = 0; t8 < 16; t8++) {
            s8v bfr = *(const s8v*)&ldsB[(t8 * 16 + lr) * 136 + kk * 32 + g * 8];
            acc[t8] = __builtin_amdgcn_mfma_f32_16x16x32_bf16(afr[kk], bfr, acc[t8], 0, 0, 0);
        }
    }

    int orow0 = rowbase + g * 4;
    #pragma unroll
    for (int r = 0; r < 4; r++) {
        int row = orow0 + r;
        if (row < M) {
            float sc = dinv[list[row]];
            #pragma unroll
            for (int t8 = 0; t8 < 16; t8++) {
                int col = t8 * 16 + lr;
                float v = sc * acc[t8][r] + b1[col];
                x1c[(size_t)row * HID + col] = f2bf(v > 0.f ? v : 0.f);
            }
        }
    }
}

// ---------------- layer-2 pre-aggregation at post slots, 4-edge ILP ----------------

__global__ void z2_kernel(const unsigned short* __restrict__ x1c, const float* __restrict__ dinv,
                          const int* __restrict__ offs, const int* __restrict__ cnt,
                          const int* __restrict__ csr, const int* __restrict__ inv,
                          const int* __restrict__ post, unsigned short* __restrict__ z2b) {
    int wave = threadIdx.x >> 6, lane = threadIdx.x & 63;
    int eg = lane >> 4, el = lane & 15;
    int p = blockIdx.x * 4 + wave;
    if (p >= NP) return;
    int node = post[p];
    int o = offs[node], c = cnt[node];
    float acc0[8] = {0.f, 0.f, 0.f, 0.f, 0.f, 0.f, 0.f, 0.f};
    float acc1[8] = {0.f, 0.f, 0.f, 0.f, 0.f, 0.f, 0.f, 0.f};
    for (int k = eg; k < c; k += 4) {
        int sv = csr[o + k];
        float wgt = dinv[sv];
        int r = inv[sv];
        const unsigned short* rp = &x1c[(size_t)r * HID + el * 16];
        s8v h0 = *(const s8v*)rp;
        s8v h1 = *(const s8v*)(rp + 8);
        #pragma unroll
        for (int j = 0; j < 8; j++) {
            acc0[j] += wgt * bf2f((unsigned short)h0[j]);
            acc1[j] += wgt * bf2f((unsigned short)h1[j]);
        }
    }
    if (eg == 0) {
        float di = dinv[node];
        int r = inv[node];
        const unsigned short* rp = &x1c[(size_t)r * HID + el * 16];
        s8v h0 = *(const s8v*)rp;
        s8v h1 = *(const s8v*)(rp + 8);
        #pragma unroll
        for (int j = 0; j < 8; j++) {
            acc0[j] += di * bf2f((unsigned short)h0[j]);
            acc1[j] += di * bf2f((unsigned short)h1[j]);
        }
    }
    #pragma unroll
    for (int j = 0; j < 8; j++) {
        acc0[j] += __shfl_xor(acc0[j], 16, 64);
        acc0[j] += __shfl_xor(acc0[j], 32, 64);
        acc1[j] += __shfl_xor(acc1[j], 16, 64);
        acc1[j] += __shfl_xor(acc1[j], 32, 64);
    }
    if (eg == 0) {
        s8v o0, o1;
        #pragma unroll
        for (int j = 0; j < 8; j++) {
            o0[j] = (short)f2bf(acc0[j]);
            o1[j] = (short)f2bf(acc1[j]);
        }
        unsigned short* wp = &z2b[(size_t)p * HID + el * 16];
        *(s8v*)wp = o0;
        *(s8v*)(wp + 8) = o1;
    }
}

// ---------------- MFMA GEMM (64 rows x 128 cols per block), EPI 2/3 ----------------
// EPI 2: aggP[row,col] += dinv[nd]*acc + bias[col] + x1c[inv[nd],col], nd=rowmap[row]
// EPI 3: out = relu(alpha*acc + bias[col]) -> f32

template<int K, int EPI>
__global__ void mfma_kernel(const unsigned short* __restrict__ A,
                            const unsigned short* __restrict__ Bt,
                            int M, int ostride,
                            const float* __restrict__ dinv,
                            const int* __restrict__ rowmap,
                            const int* __restrict__ invmap,
                            const float* __restrict__ bias,
                            const unsigned short* __restrict__ x1,
                            float alpha,
                            void* __restrict__ OutP) {
    __shared__ unsigned short lds[128 * (K + 8)];
    int tid = threadIdx.x;
    int colbase = blockIdx.y * 128;
    for (int t = tid; t < 128 * K / 4; t += 256) {
        int n = t / (K / 4);
        int k4 = (t - n * (K / 4)) * 4;
        *(ushort4*)&lds[n * (K + 8) + k4] = *(const ushort4*)&Bt[(size_t)(colbase + n) * K + k4];
    }
    __syncthreads();

    int wave = tid >> 6, lane = tid & 63, lr = lane & 15, g = lane >> 4;
    int rowbase = blockIdx.x * 64 + wave * 16;
    int arow = rowbase + lr;

    f4v acc[8];
    #pragma unroll
    for (int t = 0; t < 8; t++) acc[t] = (f4v){0.f, 0.f, 0.f, 0.f};

    #pragma unroll
    for (int kk = 0; kk < K / 32; kk++) {
        s8v a = (s8v){0, 0, 0, 0, 0, 0, 0, 0};
        if (arow < M) a = *(const s8v*)&A[(size_t)arow * K + kk * 32 + g * 8];
        #pragma unroll
        for (int t = 0; t < 8; t++) {
            s8v b = *(const s8v*)&lds[(t * 16 + lr) * (K + 8) + kk * 32 + g * 8];
            acc[t] = __builtin_amdgcn_mfma_f32_16x16x32_bf16(a, b, acc[t], 0, 0, 0);
        }
    }

    int orow0 = rowbase + g * 4;
    if (EPI == 2) {
        float* Out = (float*)OutP;
        #pragma unroll
        for (int r = 0; r < 4; r++) {
            int row = orow0 + r;
            if (row < M) {
                int nd = rowmap[row];
                float sc = dinv[nd];
                size_t x1row = (size_t)invmap[nd] * HID;
                #pragma unroll
                for (int t = 0; t < 8; t++) {
                    int col = colbase + t * 16 + lr;
                    Out[(size_t)row * ostride + col] +=
                        sc * acc[t][r] + bias[col] + bf2f(x1[x1row + col]);
                }
            }
        }
    } else {
        float* Out = (float*)OutP;
        #pragma unroll
        for (int r = 0; r < 4; r++) {
            int row = orow0 + r;
            if (row < M) {
                #pragma unroll
                for (int t = 0; t < 8; t++) {
                    int col = colbase + t * 16 + lr;
                    float v = alpha * acc[t][r] + bias[col];
                    Out[(size_t)row * ostride + col] = v > 0.f ? v : 0.f;
                }
            }
        }
    }
}

// out[p] = sigmoid(hid[p,:] . Wc2 + bc2)
__global__ void final_kernel(const float* __restrict__ hid, const float* __restrict__ Wc2,
                             const float* __restrict__ bc2, float* __restrict__ out) {
    int wave = threadIdx.x >> 6;
    int lane = threadIdx.x & 63;
    int p = blockIdx.x * 4 + wave;
    if (p >= NP) return;
    float part = hid[(size_t)p * 128 + lane] * Wc2[lane]
               + hid[(size_t)p * 128 + 64 + lane] * Wc2[64 + lane];
    for (int off = 32; off; off >>= 1) part += __shfl_down(part, off, 64);
    if (lane == 0) out[p] = 1.f / (1.f + expf(-(part + bc2[0])));
}

// ---------------- host ----------------

extern "C" void kernel_launch(void* const* d_in, const int* in_sizes, int n_in,
                              void* d_out, int out_size, void* d_ws, size_t ws_size,
                              hipStream_t stream) {
    const float* X    = (const float*)d_in[0];
    const int*   EI   = (const int*)d_in[1];
    const int*   post = (const int*)d_in[2];
    const float* W1   = (const float*)d_in[3];
    const float* b1   = (const float*)d_in[4];
    const float* W2   = (const float*)d_in[5];
    const float* b2   = (const float*)d_in[6];
    const float* Wc1  = (const float*)d_in[7];
    const float* bc1  = (const float*)d_in[8];
    const float* Wc2  = (const float*)d_in[9];
    const float* bc2  = (const float*)d_in[10];
    float* out = (float*)d_out;

    char* w = (char*)d_ws;
    auto carve = [&](size_t bytes) {
        void* p = (void*)w;
        w += (bytes + 255) & ~(size_t)255;
        return p;
    };
    unsigned short* Xb    = (unsigned short*)carve((size_t)NN * DIN * 2);   // 25.6 MB
    unsigned short* x1c   = (unsigned short*)carve((size_t)NN * HID * 2);   // 51.2 MB
    unsigned short* z2b   = (unsigned short*)carve((size_t)NP * HID * 2);   // 5.1 MB
    float* aggP           = (float*)carve((size_t)NP * HID * 4);            // 10.2 MB
    unsigned short* aggPb = (unsigned short*)carve((size_t)NP * HID * 2);   // 5.1 MB
    float* hid            = (float*)carve((size_t)NP * 128 * 4);            // 5.1 MB
    unsigned short* W1t   = (unsigned short*)carve((size_t)256 * 128 * 2);
    unsigned short* W2t   = (unsigned short*)carve((size_t)256 * 256 * 2);
    unsigned short* Wc1t  = (unsigned short*)carve((size_t)128 * 256 * 2);
    float* dinv           = (float*)carve((size_t)NS * NN * 4);             // 2 MB
    int*   cnt            = (int*)carve((size_t)NS * NN * 4);
    int*   offs           = (int*)carve((size_t)NS * NN * 4);
    int*   needed         = (int*)carve((size_t)NS * NN * 4);
    int*   list           = (int*)carve((size_t)NS * NN * 4);
    int*   inv            = (int*)carve((size_t)NS * NN * 4);
    int*   isPost         = (int*)carve((size_t)NN * 4);
    int*   bhist          = (int*)carve((size_t)NS * NBUCK * 4);
    int*   bbase          = (int*)carve((size_t)NS * NBUCK * 4);
    int*   bcur           = (int*)carve((size_t)NS * NBUCK * 4);
    int*   ncount         = (int*)carve((size_t)NS * 4);
    int*   csr            = (int*)carve((size_t)NS * NE * 4);               // 6 MB
    int2*  pairs          = (int2*)carve((size_t)NS * NE * 8);              // 12 MB

    // ---- zero-init ----
    hipMemsetAsync(aggP, 0, (size_t)NP * HID * 4, stream);
    hipMemsetAsync(needed, 0, (size_t)NS * NN * 4, stream);
    hipMemsetAsync(isPost, 0, (size_t)NN * 4, stream);
    hipMemsetAsync(bhist, 0, (size_t)NS * NBUCK * 4, stream);
    hipMemsetAsync(ncount, 0, (size_t)NS * 4, stream);

    // ---- prep ----
    cvt_kernel<<<(NN * DIN / 4 + 255) / 256, 256, 0, stream>>>(X, Xb, NN * DIN / 4);
    tw_kernel<<<(128 * 256 + 255) / 256, 256, 0, stream>>>(W1, W1t, 128, 256);
    tw_kernel<<<(256 * 256 + 255) / 256, 256, 0, stream>>>(W2, W2t, 256, 256);
    tw_kernel<<<(256 * 128 + 255) / 256, 256, 0, stream>>>(Wc1, Wc1t, 256, 128);
    setpost_kernel<<<dim3((NP + 255) / 256, NS), 256, 0, stream>>>(post, isPost, needed);

    // ---- bucket-partition CSR build (all snapshots) ----
    hist_kernel<<<dim3(PBLK, NS), 256, 0, stream>>>(EI, bhist);
    bscan_kernel<<<NS, NBUCK, 0, stream>>>(bhist, bbase, bcur);
    part_kernel<<<dim3(PBLK, NS), 256, 0, stream>>>(EI, bcur, pairs);
    bucket_csr_kernel<<<dim3(NBUCK_USED, NS), 256, 0, stream>>>(pairs, bbase, bhist, isPost,
                                                                cnt, offs, dinv, csr, needed);
    compact_kernel<<<dim3(NB_N, NS), 256, 0, stream>>>(needed, ncount, list, inv);

    // ---- per-snapshot compute ----
    for (int s = 0; s < NS; s++) {
        const float* dinv_s = dinv + (size_t)s * NN;
        const int* offs_s   = offs + (size_t)s * NN;
        const int* cnt_s    = cnt + (size_t)s * NN;
        const int* csr_s    = csr + (size_t)s * NE;
        const int* list_s   = list + (size_t)s * NN;
        const int* inv_s    = inv + (size_t)s * NN;
        const int* ncnt_s   = ncount + s;

        agg_mm1_kernel<<<(NN + 63) / 64, 256, 0, stream>>>(Xb, W1t, ncnt_s, dinv_s,
                                                           offs_s, cnt_s, csr_s, list_s,
                                                           b1, x1c);
        z2_kernel<<<(NP + 3) / 4, 256, 0, stream>>>(x1c, dinv_s, offs_s, cnt_s, csr_s,
                                                    inv_s, post, z2b);
        {
            dim3 g((NP + 63) / 64, 2);
            mfma_kernel<HID, 2><<<g, 256, 0, stream>>>(z2b, W2t, NP, HID,
                                                       dinv_s, post, inv_s,
                                                       b2, x1c, 0.f, aggP);
        }
    }

    // ---- classifier ----
    cvt_kernel<<<(NP * HID / 4 + 255) / 256, 256, 0, stream>>>(aggP, aggPb, NP * HID / 4);
    {
        dim3 g((NP + 63) / 64, 1);
        mfma_kernel<HID, 3><<<g, 256, 0, stream>>>(aggPb, Wc1t, NP, 128,
                                                   nullptr, nullptr, nullptr,
                                                   bc1, nullptr, 0.2f, hid);
    }
    final_kernel<<<(NP + 3) / 4, 256, 0, stream>>>(hid, Wc2, bc2, out);
}

// Round 5
// 394.129 us; speedup vs baseline: 2.4369x; 1.1506x over previous
//
#include <hip/hip_runtime.h>
#include <hip/hip_bf16.h>
#include <math.h>

#define NN 100000   // nodes
#define NE 300000   // edges per snapshot
#define NS 5        // snapshots
#define DIN 128
#define HID 256
#define NP 10000    // post nodes
#define NB_N 391    // ceil(NN/256)

#define NBUCK 1024      // bucket count (dst>>7), 782 used
#define NBUCK_USED 782
#define PBLK 64         // partition blocks per snapshot
#define EPB 19          // edges per thread: 64*256*19 >= NE
#define BCAP 2048       // max edges per bucket (mean 384)
#define CAPR 40960      // max compacted rows per snapshot (~33.3K expected)

typedef short s8v __attribute__((ext_vector_type(8)));   // 8 x bf16
typedef float f4v __attribute__((ext_vector_type(4)));

static __device__ __forceinline__ float bf2f(unsigned short u) {
    union { unsigned int i; float f; } v; v.i = ((unsigned int)u) << 16; return v.f;
}
static __device__ __forceinline__ unsigned short f2bf(float f) {
    union { float f; unsigned int i; } v; v.f = f;
    return (unsigned short)((v.i + 0x7fff + ((v.i >> 16) & 1)) >> 16);   // RNE
}

// ---------------- post marking ----------------

__global__ void setpost_kernel(const int* __restrict__ post, int* __restrict__ isPost,
                               int* __restrict__ needed) {
    int i = blockIdx.x * 256 + threadIdx.x;
    int s = blockIdx.y;
    if (i < NP) {
        int nd = post[i];
        needed[(size_t)s * NN + nd] = 1;
        if (s == 0) isPost[nd] = 1;
    }
}

// ---------------- bucket-partition CSR build (dense writes) ----------------

__global__ void hist_kernel(const int* __restrict__ EI, int* __restrict__ bhist) {
    __shared__ int h[NBUCK];
    int s = blockIdx.y, b = blockIdx.x, t = threadIdx.x;
    for (int q = t; q < NBUCK; q += 256) h[q] = 0;
    __syncthreads();
    const int* dstp = EI + (size_t)s * 2 * NE + NE;
    int e0 = b * (EPB * 256);
    #pragma unroll
    for (int j = 0; j < EPB; j++) {
        int e = e0 + j * 256 + t;
        if (e < NE) atomicAdd(&h[dstp[e] >> 7], 1);
    }
    __syncthreads();
    for (int q = t; q < NBUCK; q += 256)
        if (h[q]) atomicAdd(&bhist[s * NBUCK + q], h[q]);
}

__global__ void bscan_kernel(const int* __restrict__ bhist, int* __restrict__ bbase,
                             int* __restrict__ bcur) {
    __shared__ int sm[NBUCK];
    int s = blockIdx.x, t = threadIdx.x;
    int v = bhist[s * NBUCK + t];
    sm[t] = v;
    __syncthreads();
    for (int d = 1; d < NBUCK; d <<= 1) {
        int x = (t >= d) ? sm[t - d] : 0;
        __syncthreads();
        sm[t] += x;
        __syncthreads();
    }
    int base = sm[t] - v;
    bbase[s * NBUCK + t] = base;
    bcur[s * NBUCK + t] = base;
}

__global__ void part_kernel(const int* __restrict__ EI, int* __restrict__ bcur,
                            int2* __restrict__ pairs) {
    __shared__ int h[NBUCK];
    __shared__ int base[NBUCK];
    int s = blockIdx.y, b = blockIdx.x, t = threadIdx.x;
    for (int q = t; q < NBUCK; q += 256) h[q] = 0;
    __syncthreads();
    const int* srcp = EI + (size_t)s * 2 * NE;
    const int* dstp = srcp + NE;
    int e0 = b * (EPB * 256);
    int rs[EPB], rd[EPB];
    #pragma unroll
    for (int j = 0; j < EPB; j++) {
        int e = e0 + j * 256 + t;
        if (e < NE) {
            rs[j] = srcp[e];
            rd[j] = dstp[e];
            atomicAdd(&h[rd[j] >> 7], 1);
        } else {
            rd[j] = -1; rs[j] = 0;
        }
    }
    __syncthreads();
    for (int q = t; q < NBUCK; q += 256) {
        int c = h[q];
        base[q] = c ? atomicAdd(&bcur[s * NBUCK + q], c) : 0;
    }
    __syncthreads();
    #pragma unroll
    for (int j = 0; j < EPB; j++) {
        if (rd[j] >= 0) {
            int pos = atomicAdd(&base[rd[j] >> 7], 1);
            pairs[(size_t)s * NE + pos] = make_int2(rs[j], rd[j]);
        }
    }
}

__global__ void bucket_csr_kernel(const int2* __restrict__ pairs, const int* __restrict__ bbase,
                                  const int* __restrict__ bhist, const int* __restrict__ isPost,
                                  int* __restrict__ cnt, int* __restrict__ offs,
                                  float* __restrict__ dinv, int* __restrict__ csr,
                                  int* __restrict__ needed) {
    __shared__ int nh[128];
    __shared__ int noff[128];
    __shared__ int sbuf[BCAP];
    int s = blockIdx.y, b = blockIdx.x, t = threadIdx.x;
    int base = bbase[s * NBUCK + b];
    int count = bhist[s * NBUCK + b];
    if (count > BCAP) count = BCAP;   // statistically unreachable
    if (t < 128) nh[t] = 0;
    __syncthreads();
    const int2* pp = pairs + (size_t)s * NE + base;
    for (int e = t; e < count; e += 256)
        atomicAdd(&nh[pp[e].y & 127], 1);
    __syncthreads();
    if (t < 128) noff[t] = nh[t];
    __syncthreads();
    for (int d = 1; d < 128; d <<= 1) {
        int x = 0;
        if (t < 128 && t >= d) x = noff[t - d];
        __syncthreads();
        if (t < 128) noff[t] += x;
        __syncthreads();
    }
    if (t < 128) {
        int excl = noff[t] - nh[t];
        noff[t] = excl;
        int g = b * 128 + t;
        if (g < NN) {
            int c = nh[t];
            cnt[(size_t)s * NN + g]  = c;
            offs[(size_t)s * NN + g] = base + excl;
            dinv[(size_t)s * NN + g] = rsqrtf((float)(c + 1));   // +1 self loop
        }
    }
    __syncthreads();
    for (int e = t; e < count; e += 256) {
        int2 pr = pp[e];
        int pos = atomicAdd(&noff[pr.y & 127], 1);
        sbuf[pos] = pr.x;
        if (isPost[pr.y]) needed[(size_t)s * NN + pr.x] = 1;
    }
    __syncthreads();
    for (int e = t; e < count; e += 256)
        csr[(size_t)s * NE + base + e] = sbuf[e];
}

// ---------------- needed-set compaction, wave-aggregated atomic ----------------

__global__ void compact_kernel(const int* __restrict__ needed, int* __restrict__ ncount,
                               int* __restrict__ list, int* __restrict__ inv) {
    int s = blockIdx.y;
    int i = blockIdx.x * 256 + threadIdx.x;
    int lane = threadIdx.x & 63;
    bool pred = (i < NN) && (needed[(size_t)s * NN + i] != 0);
    unsigned long long mask = __ballot(pred);
    if (mask == 0ull) return;
    int leader = __ffsll((unsigned long long)mask) - 1;
    int cntw = __popcll(mask);
    int base = 0;
    if (lane == leader) base = atomicAdd(&ncount[s], cntw);
    base = __shfl(base, leader, 64);
    if (pred) {
        int rank = __popcll(mask & ((1ull << lane) - 1ull));
        int slot = base + rank;
        if (slot < CAPR) {
            list[(size_t)s * NN + slot] = i;
            inv[(size_t)s * NN + i] = slot;
        }
    }
}

// ---------------- dtype prep ----------------

__global__ void cvt_kernel(const float* __restrict__ src, unsigned short* __restrict__ dstp, int n4) {
    int i = blockIdx.x * 256 + threadIdx.x;
    if (i < n4) {
        float4 v = *(const float4*)&src[(size_t)i * 4];
        ushort4 o;
        o.x = f2bf(v.x); o.y = f2bf(v.y); o.z = f2bf(v.z); o.w = f2bf(v.w);
        *(ushort4*)&dstp[(size_t)i * 4] = o;
    }
}

// W [K,Ncols] f32 -> Wt [Ncols,K] bf16
__global__ void tw_kernel(const float* __restrict__ W, unsigned short* __restrict__ Wt,
                          int K, int Ncols) {
    int i = blockIdx.x * 256 + threadIdx.x;
    if (i < K * Ncols) {
        int n = i / K, k = i - n * K;
        Wt[i] = f2bf(W[(size_t)k * Ncols + n]);
    }
}

// ---------------- fused layer-1 (batched over snapshots via blockIdx.y) ----------------
// Register-gather aggregate (K=128) + MFMA vs W1t in LDS -> x1c slab per snapshot.

__global__ __launch_bounds__(256) void agg_mm1_kernel(
        const unsigned short* __restrict__ Xb, const unsigned short* __restrict__ W1t,
        const int* __restrict__ ncount, const float* __restrict__ dinvA,
        const int* __restrict__ offsA, const int* __restrict__ cntA,
        const int* __restrict__ csrA, const int* __restrict__ listA,
        const float* __restrict__ b1, unsigned short* __restrict__ x1cA) {
    int s = blockIdx.y;
    int M = ncount[s];
    if (M > CAPR) M = CAPR;
    if (blockIdx.x * 64 >= M) return;
    const float* dinv = dinvA + (size_t)s * NN;
    const int* offs = offsA + (size_t)s * NN;
    const int* cnt  = cntA + (size_t)s * NN;
    const int* csr  = csrA + (size_t)s * NE;
    const int* list = listA + (size_t)s * NN;
    unsigned short* x1c = x1cA + (size_t)s * CAPR * HID;

    __shared__ unsigned short ldsB[256 * 136];   // [n][k], +8 pad -> 2-way banks (free)
    int tid = threadIdx.x;
    for (int q = tid; q < 256 * 16; q += 256) {
        int n = q >> 4;
        int k8 = (q & 15) * 8;
        *(s8v*)&ldsB[n * 136 + k8] = *(const s8v*)&W1t[n * 128 + k8];
    }
    __syncthreads();

    int wave = tid >> 6, lane = tid & 63, lr = lane & 15, g = lane >> 4;
    int rowbase = blockIdx.x * 64 + wave * 16;
    int arow = rowbase + lr;

    float ga[4][8];
    #pragma unroll
    for (int kk = 0; kk < 4; kk++)
        #pragma unroll
        for (int j = 0; j < 8; j++) ga[kk][j] = 0.f;

    if (arow < M) {
        int node = list[arow];
        int o = offs[node], c = cnt[node];
        float di = dinv[node];
        const unsigned short* rp = Xb + (size_t)node * DIN + g * 8;
        #pragma unroll
        for (int kk = 0; kk < 4; kk++) {
            s8v h = *(const s8v*)(rp + kk * 32);
            #pragma unroll
            for (int j = 0; j < 8; j++) ga[kk][j] = di * bf2f((unsigned short)h[j]);
        }
        for (int k = 0; k < c; k++) {
            int sv = csr[o + k];
            float wgt = dinv[sv];
            const unsigned short* sp = Xb + (size_t)sv * DIN + g * 8;
            #pragma unroll
            for (int kk = 0; kk < 4; kk++) {
                s8v h = *(const s8v*)(sp + kk * 32);
                #pragma unroll
                for (int j = 0; j < 8; j++) ga[kk][j] += wgt * bf2f((unsigned short)h[j]);
            }
        }
    }

    s8v afr[4];
    #pragma unroll
    for (int kk = 0; kk < 4; kk++)
        #pragma unroll
        for (int j = 0; j < 8; j++) afr[kk][j] = (short)f2bf(ga[kk][j]);

    f4v acc[16];
    #pragma unroll
    for (int t8 = 0; t8 < 16; t8++) acc[t8] = (f4v){0.f, 0.f, 0.f, 0.f};
    #pragma unroll
    for (int kk = 0; kk < 4; kk++) {
        #pragma unroll
        for (int t8 = 0; t8 < 16; t8++) {
            s8v bfr = *(const s8v*)&ldsB[(t8 * 16 + lr) * 136 + kk * 32 + g * 8];
            acc[t8] = __builtin_amdgcn_mfma_f32_16x16x32_bf16(afr[kk], bfr, acc[t8], 0, 0, 0);
        }
    }

    int orow0 = rowbase + g * 4;
    #pragma unroll
    for (int r = 0; r < 4; r++) {
        int row = orow0 + r;
        if (row < M) {
            float sc = dinv[list[row]];
            #pragma unroll
            for (int t8 = 0; t8 < 16; t8++) {
                int col = t8 * 16 + lr;
                float v = sc * acc[t8][r] + b1[col];
                x1c[(size_t)row * HID + col] = f2bf(v > 0.f ? v : 0.f);
            }
        }
    }
}

// ---------------- layer-2 pre-aggregation at post slots, 4-edge ILP, batched ---------

__global__ void z2_kernel(const unsigned short* __restrict__ x1cA, const float* __restrict__ dinvA,
                          const int* __restrict__ offsA, const int* __restrict__ cntA,
                          const int* __restrict__ csrA, const int* __restrict__ invA,
                          const int* __restrict__ post, unsigned short* __restrict__ z2bA) {
    int s = blockIdx.y;
    const unsigned short* x1c = x1cA + (size_t)s * CAPR * HID;
    const float* dinv = dinvA + (size_t)s * NN;
    const int* offs = offsA + (size_t)s * NN;
    const int* cnt  = cntA + (size_t)s * NN;
    const int* csr  = csrA + (size_t)s * NE;
    const int* inv  = invA + (size_t)s * NN;
    unsigned short* z2b = z2bA + (size_t)s * NP * HID;

    int wave = threadIdx.x >> 6, lane = threadIdx.x & 63;
    int eg = lane >> 4, el = lane & 15;
    int p = blockIdx.x * 4 + wave;
    if (p >= NP) return;
    int node = post[p];
    int o = offs[node], c = cnt[node];
    float acc0[8] = {0.f, 0.f, 0.f, 0.f, 0.f, 0.f, 0.f, 0.f};
    float acc1[8] = {0.f, 0.f, 0.f, 0.f, 0.f, 0.f, 0.f, 0.f};
    for (int k = eg; k < c; k += 4) {
        int sv = csr[o + k];
        float wgt = dinv[sv];
        int r = inv[sv];
        const unsigned short* rp = &x1c[(size_t)r * HID + el * 16];
        s8v h0 = *(const s8v*)rp;
        s8v h1 = *(const s8v*)(rp + 8);
        #pragma unroll
        for (int j = 0; j < 8; j++) {
            acc0[j] += wgt * bf2f((unsigned short)h0[j]);
            acc1[j] += wgt * bf2f((unsigned short)h1[j]);
        }
    }
    if (eg == 0) {
        float di = dinv[node];
        int r = inv[node];
        const unsigned short* rp = &x1c[(size_t)r * HID + el * 16];
        s8v h0 = *(const s8v*)rp;
        s8v h1 = *(const s8v*)(rp + 8);
        #pragma unroll
        for (int j = 0; j < 8; j++) {
            acc0[j] += di * bf2f((unsigned short)h0[j]);
            acc1[j] += di * bf2f((unsigned short)h1[j]);
        }
    }
    #pragma unroll
    for (int j = 0; j < 8; j++) {
        acc0[j] += __shfl_xor(acc0[j], 16, 64);
        acc0[j] += __shfl_xor(acc0[j], 32, 64);
        acc1[j] += __shfl_xor(acc1[j], 16, 64);
        acc1[j] += __shfl_xor(acc1[j], 32, 64);
    }
    if (eg == 0) {
        s8v o0, o1;
        #pragma unroll
        for (int j = 0; j < 8; j++) {
            o0[j] = (short)f2bf(acc0[j]);
            o1[j] = (short)f2bf(acc1[j]);
        }
        unsigned short* wp = &z2b[(size_t)p * HID + el * 16];
        *(s8v*)wp = o0;
        *(s8v*)(wp + 8) = o1;
    }
}

// ---------------- layer-2 GEMM, batched: aggP5[s] = dinv*acc + b2 + x1 residual --------

__global__ void mm2_kernel(const unsigned short* __restrict__ z2bA,
                           const unsigned short* __restrict__ W2t,
                           const float* __restrict__ dinvA,
                           const int* __restrict__ post,
                           const int* __restrict__ invA,
                           const float* __restrict__ b2,
                           const unsigned short* __restrict__ x1cA,
                           float* __restrict__ aggPA) {
    int s = blockIdx.z;
    const unsigned short* A = z2bA + (size_t)s * NP * HID;
    const float* dinv = dinvA + (size_t)s * NN;
    const int* inv = invA + (size_t)s * NN;
    const unsigned short* x1c = x1cA + (size_t)s * CAPR * HID;
    float* Out = aggPA + (size_t)s * NP * HID;

    __shared__ unsigned short lds[128 * (HID + 8)];
    int tid = threadIdx.x;
    int colbase = blockIdx.y * 128;
    for (int t = tid; t < 128 * HID / 4; t += 256) {
        int n = t / (HID / 4);
        int k4 = (t - n * (HID / 4)) * 4;
        *(ushort4*)&lds[n * (HID + 8) + k4] = *(const ushort4*)&W2t[(size_t)(colbase + n) * HID + k4];
    }
    __syncthreads();

    int wave = tid >> 6, lane = tid & 63, lr = lane & 15, g = lane >> 4;
    int rowbase = blockIdx.x * 64 + wave * 16;
    int arow = rowbase + lr;

    f4v acc[8];
    #pragma unroll
    for (int t = 0; t < 8; t++) acc[t] = (f4v){0.f, 0.f, 0.f, 0.f};

    #pragma unroll
    for (int kk = 0; kk < HID / 32; kk++) {
        s8v a = (s8v){0, 0, 0, 0, 0, 0, 0, 0};
        if (arow < NP) a = *(const s8v*)&A[(size_t)arow * HID + kk * 32 + g * 8];
        #pragma unroll
        for (int t = 0; t < 8; t++) {
            s8v b = *(const s8v*)&lds[(t * 16 + lr) * (HID + 8) + kk * 32 + g * 8];
            acc[t] = __builtin_amdgcn_mfma_f32_16x16x32_bf16(a, b, acc[t], 0, 0, 0);
        }
    }

    int orow0 = rowbase + g * 4;
    #pragma unroll
    for (int r = 0; r < 4; r++) {
        int row = orow0 + r;
        if (row < NP) {
            int nd = post[row];
            float sc = dinv[nd];
            size_t x1row = (size_t)inv[nd] * HID;
            #pragma unroll
            for (int t = 0; t < 8; t++) {
                int col = colbase + t * 16 + lr;
                Out[(size_t)row * HID + col] =
                    sc * acc[t][r] + b2[col] + bf2f(x1c[x1row + col]);
            }
        }
    }
}

// ---------------- reduce 5 aggP slabs -> bf16 ----------------

__global__ void redcvt_kernel(const float* __restrict__ aggPA, unsigned short* __restrict__ aggPb) {
    int i = blockIdx.x * 256 + threadIdx.x;
    if (i < NP * HID / 4) {
        float4 a = *(const float4*)&aggPA[(size_t)i * 4];
        #pragma unroll
        for (int s = 1; s < NS; s++) {
            float4 b = *(const float4*)&aggPA[(size_t)s * NP * HID + (size_t)i * 4];
            a.x += b.x; a.y += b.y; a.z += b.z; a.w += b.w;
        }
        ushort4 o;
        o.x = f2bf(a.x); o.y = f2bf(a.y); o.z = f2bf(a.z); o.w = f2bf(a.w);
        *(ushort4*)&aggPb[(size_t)i * 4] = o;
    }
}

// ---------------- classifier GEMM: hid = relu(0.2*aggPb@Wc1 + bc1) ----------------

__global__ void mm3_kernel(const unsigned short* __restrict__ A,
                           const unsigned short* __restrict__ Bt,
                           const float* __restrict__ bias,
                           float* __restrict__ Out) {
    __shared__ unsigned short lds[128 * (HID + 8)];
    int tid = threadIdx.x;
    for (int t = tid; t < 128 * HID / 4; t += 256) {
        int n = t / (HID / 4);
        int k4 = (t - n * (HID / 4)) * 4;
        *(ushort4*)&lds[n * (HID + 8) + k4] = *(const ushort4*)&Bt[(size_t)n * HID + k4];
    }
    __syncthreads();

    int wave = tid >> 6, lane = tid & 63, lr = lane & 15, g = lane >> 4;
    int rowbase = blockIdx.x * 64 + wave * 16;
    int arow = rowbase + lr;

    f4v acc[8];
    #pragma unroll
    for (int t = 0; t < 8; t++) acc[t] = (f4v){0.f, 0.f, 0.f, 0.f};

    #pragma unroll
    for (int kk = 0; kk < HID / 32; kk++) {
        s8v a = (s8v){0, 0, 0, 0, 0, 0, 0, 0};
        if (arow < NP) a = *(const s8v*)&A[(size_t)arow * HID + kk * 32 + g * 8];
        #pragma unroll
        for (int t = 0; t < 8; t++) {
            s8v b = *(const s8v*)&lds[(t * 16 + lr) * (HID + 8) + kk * 32 + g * 8];
            acc[t] = __builtin_amdgcn_mfma_f32_16x16x32_bf16(a, b, acc[t], 0, 0, 0);
        }
    }

    int orow0 = rowbase + g * 4;
    #pragma unroll
    for (int r = 0; r < 4; r++) {
        int row = orow0 + r;
        if (row < NP) {
            #pragma unroll
            for (int t = 0; t < 8; t++) {
                int col = t * 16 + lr;
                float v = 0.2f * acc[t][r] + bias[col];
                Out[(size_t)row * 128 + col] = v > 0.f ? v : 0.f;
            }
        }
    }
}

// out[p] = sigmoid(hid[p,:] . Wc2 + bc2)
__global__ void final_kernel(const float* __restrict__ hid, const float* __restrict__ Wc2,
                             const float* __restrict__ bc2, float* __restrict__ out) {
    int wave = threadIdx.x >> 6;
    int lane = threadIdx.x & 63;
    int p = blockIdx.x * 4 + wave;
    if (p >= NP) return;
    float part = hid[(size_t)p * 128 + lane] * Wc2[lane]
               + hid[(size_t)p * 128 + 64 + lane] * Wc2[64 + lane];
    for (int off = 32; off; off >>= 1) part += __shfl_down(part, off, 64);
    if (lane == 0) out[p] = 1.f / (1.f + expf(-(part + bc2[0])));
}

// ---------------- host ----------------

extern "C" void kernel_launch(void* const* d_in, const int* in_sizes, int n_in,
                              void* d_out, int out_size, void* d_ws, size_t ws_size,
                              hipStream_t stream) {
    const float* X    = (const float*)d_in[0];
    const int*   EI   = (const int*)d_in[1];
    const int*   post = (const int*)d_in[2];
    const float* W1   = (const float*)d_in[3];
    const float* b1   = (const float*)d_in[4];
    const float* W2   = (const float*)d_in[5];
    const float* b2   = (const float*)d_in[6];
    const float* Wc1  = (const float*)d_in[7];
    const float* bc1  = (const float*)d_in[8];
    const float* Wc2  = (const float*)d_in[9];
    const float* bc2  = (const float*)d_in[10];
    float* out = (float*)d_out;

    char* w = (char*)d_ws;
    auto carve = [&](size_t bytes) {
        void* p = (void*)w;
        w += (bytes + 255) & ~(size_t)255;
        return p;
    };
    unsigned short* Xb    = (unsigned short*)carve((size_t)NN * DIN * 2);        // 25.6 MB
    unsigned short* x1c   = (unsigned short*)carve((size_t)NS * CAPR * HID * 2); // 104.9 MB
    unsigned short* z2b5  = (unsigned short*)carve((size_t)NS * NP * HID * 2);   // 25.6 MB
    float* aggP5          = (float*)carve((size_t)NS * NP * HID * 4);            // 51.2 MB
    unsigned short* aggPb = (unsigned short*)carve((size_t)NP * HID * 2);        // 5.1 MB
    float* hid            = (float*)carve((size_t)NP * 128 * 4);                 // 5.1 MB
    unsigned short* W1t   = (unsigned short*)carve((size_t)256 * 128 * 2);
    unsigned short* W2t   = (unsigned short*)carve((size_t)256 * 256 * 2);
    unsigned short* Wc1t  = (unsigned short*)carve((size_t)128 * 256 * 2);
    float* dinv           = (float*)carve((size_t)NS * NN * 4);
    int*   cnt            = (int*)carve((size_t)NS * NN * 4);
    int*   offs           = (int*)carve((size_t)NS * NN * 4);
    int*   needed         = (int*)carve((size_t)NS * NN * 4);
    int*   list           = (int*)carve((size_t)NS * NN * 4);
    int*   inv            = (int*)carve((size_t)NS * NN * 4);
    int*   isPost         = (int*)carve((size_t)NN * 4);
    int*   bhist          = (int*)carve((size_t)NS * NBUCK * 4);
    int*   bbase          = (int*)carve((size_t)NS * NBUCK * 4);
    int*   bcur           = (int*)carve((size_t)NS * NBUCK * 4);
    int*   ncount         = (int*)carve((size_t)NS * 4);
    int*   csr            = (int*)carve((size_t)NS * NE * 4);                    // 6 MB
    // pairs aliased into x1c region: lifetimes don't overlap (build before compute)
    int2*  pairs          = (int2*)x1c;                                          // 12 MB < slab

    // ---- zero-init ----
    hipMemsetAsync(needed, 0, (size_t)NS * NN * 4, stream);
    hipMemsetAsync(isPost, 0, (size_t)NN * 4, stream);
    hipMemsetAsync(bhist, 0, (size_t)NS * NBUCK * 4, stream);
    hipMemsetAsync(ncount, 0, (size_t)NS * 4, stream);

    // ---- prep ----
    cvt_kernel<<<(NN * DIN / 4 + 255) / 256, 256, 0, stream>>>(X, Xb, NN * DIN / 4);
    tw_kernel<<<(128 * 256 + 255) / 256, 256, 0, stream>>>(W1, W1t, 128, 256);
    tw_kernel<<<(256 * 256 + 255) / 256, 256, 0, stream>>>(W2, W2t, 256, 256);
    tw_kernel<<<(256 * 128 + 255) / 256, 256, 0, stream>>>(Wc1, Wc1t, 256, 128);
    setpost_kernel<<<dim3((NP + 255) / 256, NS), 256, 0, stream>>>(post, isPost, needed);

    // ---- bucket-partition CSR build (all snapshots) ----
    hist_kernel<<<dim3(PBLK, NS), 256, 0, stream>>>(EI, bhist);
    bscan_kernel<<<NS, NBUCK, 0, stream>>>(bhist, bbase, bcur);
    part_kernel<<<dim3(PBLK, NS), 256, 0, stream>>>(EI, bcur, pairs);
    bucket_csr_kernel<<<dim3(NBUCK_USED, NS), 256, 0, stream>>>(pairs, bbase, bhist, isPost,
                                                                cnt, offs, dinv, csr, needed);
    compact_kernel<<<dim3(NB_N, NS), 256, 0, stream>>>(needed, ncount, list, inv);

    // ---- batched compute (one dispatch per phase for all snapshots) ----
    agg_mm1_kernel<<<dim3((CAPR + 63) / 64, NS), 256, 0, stream>>>(
        Xb, W1t, ncount, dinv, offs, cnt, csr, list, b1, x1c);
    z2_kernel<<<dim3((NP + 3) / 4, NS), 256, 0, stream>>>(
        x1c, dinv, offs, cnt, csr, inv, post, z2b5);
    mm2_kernel<<<dim3((NP + 63) / 64, 2, NS), 256, 0, stream>>>(
        z2b5, W2t, dinv, post, inv, b2, x1c, aggP5);

    // ---- classifier ----
    redcvt_kernel<<<(NP * HID / 4 + 255) / 256, 256, 0, stream>>>(aggP5, aggPb);
    mm3_kernel<<<(NP + 63) / 64, 256, 0, stream>>>(aggPb, Wc1t, bc1, hid);
    final_kernel<<<(NP + 3) / 4, 256, 0, stream>>>(hid, Wc2, bc2, out);
}